// Round 4
// baseline (541814.941 us; speedup 1.0000x reference)
//
#include <hip/hip_runtime.h>
#include <math.h>

#define S_LEN 2048
#define FIN 9
#define NOUT 8
#define LBK 3
#define DD 11
#define K1 33
#define H2 512
#define UU 256
#define NSTEP 2044
#define MR 8
#define GRID 128
#define LN_EPS 1e-3f

typedef __attribute__((ext_vector_type(8))) short short8;
typedef __attribute__((ext_vector_type(4))) float f32x4;
typedef __attribute__((ext_vector_type(4))) unsigned short us4;

// ---- packed B-fragment pool (bf16): tile (nt,kt): 64 lanes x 8 bf16,
// elem = B[k][n], k = kt*32 + (lane>>4)*8 + j, n = nt*16 + (lane&15)
#define F_EW1 (32 * 2 * 512)
#define F_EW2 (16 * 16 * 512)
#define F_UW  (16 * 8 * 512)
#define F_DW1 (32 * 8 * 512)
#define F_DW2 (1 * 16 * 512)
#define O_EW1 0
#define O_EW2 (O_EW1 + F_EW1)
#define O_UW  (O_EW2 + F_EW2)
#define O_DW1 (O_UW + F_UW)
#define O_DW2 (O_DW1 + F_DW1)
#define W_TOT (O_DW2 + F_DW2)   // 368640 elems = 737280 B

__device__ __forceinline__ unsigned short f2bf(float f) {
    unsigned u = __float_as_uint(f);
    u = (u + 0x7fffu + ((u >> 16) & 1u)) >> 16;
    return (unsigned short)u;
}
__device__ __forceinline__ float bf2f(unsigned short u) {
    return __uint_as_float(((unsigned)u) << 16);
}
__device__ __forceinline__ float ftanh(float x) {
    float ax = fabsf(x);
    float e = __expf(-2.0f * ax);
    float r = __fdividef(1.0f - e, 1.0f + e);
    return copysignf(r, x);
}

extern "C" __global__ void convw(const float* __restrict__ ew1, const float* __restrict__ ew2,
                                 const float* __restrict__ uw,  const float* __restrict__ dw1,
                                 const float* __restrict__ dw2, unsigned short* __restrict__ o)
{
    int i = blockIdx.x * blockDim.x + threadIdx.x;
    if (i >= W_TOT) return;
    int p, KT, K, N; const float* W;
    if (i < O_EW2)      { p = i - O_EW1; KT = 2;  K = 33;  N = 512; W = ew1; }
    else if (i < O_UW)  { p = i - O_EW2; KT = 16; K = 512; N = 256; W = ew2; }
    else if (i < O_DW1) { p = i - O_UW;  KT = 8;  K = 256; N = 256; W = uw;  }
    else if (i < O_DW2) { p = i - O_DW1; KT = 8;  K = 256; N = 512; W = dw1; }
    else                { p = i - O_DW2; KT = 16; K = 512; N = 8;   W = dw2; }
    int frag = p >> 9, rem = p & 511;
    int ln = rem >> 3, j = rem & 7;
    int nt = frag / KT, kt = frag % KT;
    int k = kt * 32 + (ln >> 4) * 8 + j;
    int n = nt * 16 + (ln & 15);
    float v = 0.f;
    if (k < K && n < N) v = W[k * N + n];
    o[i] = f2bf(v);
}

extern "C" __global__ void __launch_bounds__(1024, 4)
solver(const float* __restrict__ inputs,
       const unsigned short* __restrict__ pool,
       const float* __restrict__ g1v, const float* __restrict__ b1v,
       const float* __restrict__ eb1, const float* __restrict__ eb2,
       const float* __restrict__ ub,  const float* __restrict__ g2v,
       const float* __restrict__ b2v, const float* __restrict__ bww,
       const float* __restrict__ dw1, const float* __restrict__ db1,
       const float* __restrict__ db2, const int* __restrict__ fixv,
       float* __restrict__ out)
{
    __shared__ unsigned short xs[2][MR * 72];   // LN1 out, double-buffered (33 used, zeros to 64)
    __shared__ unsigned short h1[MR * 520];     // tanh(enc1)
    __shared__ unsigned short hsb[MR * 264];    // enc2 out
    __shared__ __align__(16) float uu[MR * 260];// upd out fp32
    __shared__ unsigned short cmb[MR * 264];    // LN2 out bf16
    __shared__ unsigned short gsb[MR * 520];    // tanh(dec1)
    __shared__ float red2[16][MR][9];           // G partials (16 waves)
    __shared__ float ects[MR];
    __shared__ float s_g1[DD], s_b1[DD];
    __shared__ __align__(16) float s_g2[256], s_b2[256], s_bw[256];

    const int tid = threadIdx.x;
    const int lane = tid & 63;
    const int wv = tid >> 6;      // 0..15
    const int q = lane >> 4;      // 0..3
    const int lc = lane & 15;     // tile col / output col
    const int lr = lc & 7;        // A-row (rows 8..15 duplicate 0..7)
    const int b0 = blockIdx.x * MR;
    const int fx0 = fixv[0], fx1 = fixv[1];

    // ---- preamble ----
    for (int z = tid; z < 2 * MR * 72; z += 1024) (&xs[0][0])[z] = 0;
    for (int z = tid; z < 256; z += 1024) { s_g2[z] = g2v[z]; s_b2[z] = b2v[z]; s_bw[z] = bww[z]; }
    if (tid >= 256 && tid < 256 + DD) { s_g1[tid - 256] = g1v[tid - 256]; s_b1[tid - 256] = b1v[tid - 256]; }

    // ---- pinned step-invariant fragments (baseline budget: 36 regs) ----
    short8 fD[8];
    #pragma unroll
    for (int kt = 0; kt < 8; ++kt)
        fD[kt] = *(const short8*)&pool[O_UW + (((wv << 3) + kt) << 9) + (lane << 3)];
    short8 fG = *(const short8*)&pool[O_DW2 + (wv << 9) + (lane << 3)];

    // per-wave bias/scale scalars
    const float bB0 = eb1[(2 * wv) * 16 + lc];
    const float bB1 = eb1[(2 * wv + 1) * 16 + lc];
    const float bC  = eb2[wv * 16 + lc];
    const float bD  = ub[wv * 16 + lc];
    const float bF0 = db1[(2 * wv) * 16 + lc];
    const float bF1 = db1[(2 * wv + 1) * 16 + lc];
    const float wE0 = dw1[256 * 512 + (2 * wv) * 16 + lc];
    const float wE1 = dw1[256 * 512 + (2 * wv + 1) * 16 + lc];
    const float db2r = db2[lane & 7];

    __syncthreads();

    // ---- stage A for t=0 (window rows straight from inputs) ----
    if (tid < MR * LBK) {
        int r = tid / LBK, p = tid % LBK;
        int b = b0 + r;
        float ld = inputs[((size_t)b * S_LEN + p) * FIN];
        float df = (p > 0) ? ld - inputs[((size_t)b * S_LEN + p - 1) * FIN] : 0.f;
        float v[DD];
        v[0] = ld; v[1] = ld; v[2] = df;
        #pragma unroll
        for (int f = 0; f < NOUT; ++f) v[3 + f] = inputs[((size_t)b * S_LEN + p) * FIN + 1 + f];
        float m = 0.f;
        #pragma unroll
        for (int j = 0; j < DD; ++j) m += v[j];
        m *= (1.0f / DD);
        float var = 0.f;
        #pragma unroll
        for (int j = 0; j < DD; ++j) { float d = v[j] - m; var += d * d; }
        var *= (1.0f / DD);
        float rs = rsqrtf(var + LN_EPS);
        #pragma unroll
        for (int j = 0; j < DD; ++j)
            xs[0][r * 72 + p * DD + j] = f2bf((v[j] - m) * rs * s_g1[j] + s_b1[j]);
    }
    __syncthreads();

    for (int t = 0; t < NSTEP; ++t) {
        unsigned short* xc = &xs[t & 1][0];
        unsigned short* xn = &xs[(t & 1) ^ 1][0];

        // ---- wave 0: prefetch finalize inputs for THIS step; latency hides under B..F ----
        float pLd = 0.f, pPrev = 0.f, pF0 = 0.f, pF1 = 0.f;
        if (wv == 0) {
            const int r8 = lane & 7;
            const int rr = lane >> 3;
            pLd   = inputs[((size_t)(b0 + r8) * S_LEN + t + 3) * FIN];
            pPrev = inputs[((size_t)(b0 + r8) * S_LEN + t + 2) * FIN];
            pF0   = inputs[((size_t)(b0 + rr) * S_LEN + t + 4) * FIN + 1 + fx0];
            pF1   = inputs[((size_t)(b0 + rr) * S_LEN + t + 4) * FIN + 1 + fx1];
        }

        // ==== stage B: h1 = tanh(x @ ew1 + eb1), 33(pad64)->512 ; 16 waves x 2 tiles (streamed) ====
        {
            short8 a0 = *(const short8*)&xc[lr * 72 + q * 8];
            short8 a1 = *(const short8*)&xc[lr * 72 + 32 + q * 8];
            short8 b00 = *(const short8*)&pool[O_EW1 + ((((2 * wv)     << 1) + 0) << 9) + (lane << 3)];
            short8 b01 = *(const short8*)&pool[O_EW1 + ((((2 * wv)     << 1) + 1) << 9) + (lane << 3)];
            short8 b10 = *(const short8*)&pool[O_EW1 + ((((2 * wv + 1) << 1) + 0) << 9) + (lane << 3)];
            short8 b11 = *(const short8*)&pool[O_EW1 + ((((2 * wv + 1) << 1) + 1) << 9) + (lane << 3)];
            f32x4 acc0 = {bB0, bB0, bB0, bB0};
            f32x4 acc1 = {bB1, bB1, bB1, bB1};
            acc0 = __builtin_amdgcn_mfma_f32_16x16x32_bf16(a0, b00, acc0, 0, 0, 0);
            acc0 = __builtin_amdgcn_mfma_f32_16x16x32_bf16(a1, b01, acc0, 0, 0, 0);
            acc1 = __builtin_amdgcn_mfma_f32_16x16x32_bf16(a0, b10, acc1, 0, 0, 0);
            acc1 = __builtin_amdgcn_mfma_f32_16x16x32_bf16(a1, b11, acc1, 0, 0, 0);
            if (q < 2) {
                const int c0 = (2 * wv) * 16 + lc, c1 = (2 * wv + 1) * 16 + lc;
                #pragma unroll
                for (int r = 0; r < 4; ++r) {
                    h1[(q * 4 + r) * 520 + c0] = f2bf(ftanh(acc0[r]));
                    h1[(q * 4 + r) * 520 + c1] = f2bf(ftanh(acc1[r]));
                }
            }
        }
        __syncthreads();

        // ==== stage C: h = h1 @ ew2 + eb2, 512->256 ; 16 waves x 1 tile (streamed B) ====
        {
            f32x4 c0 = {bC, bC, bC, bC};
            f32x4 c1 = {0.f, 0.f, 0.f, 0.f};
            #pragma unroll 4
            for (int k = 0; k < 16; ++k) {
                short8 av = *(const short8*)&h1[lr * 520 + k * 32 + q * 8];
                short8 bf = *(const short8*)&pool[O_EW2 + (((wv << 4) + k) << 9) + (lane << 3)];
                if (k & 1) c1 = __builtin_amdgcn_mfma_f32_16x16x32_bf16(av, bf, c1, 0, 0, 0);
                else       c0 = __builtin_amdgcn_mfma_f32_16x16x32_bf16(av, bf, c0, 0, 0, 0);
            }
            c0 += c1;
            if (q < 2) {
                const int col = wv * 16 + lc;
                #pragma unroll
                for (int r = 0; r < 4; ++r)
                    hsb[(q * 4 + r) * 264 + col] = f2bf(c0[r]);
            }
        }
        __syncthreads();

        // ==== stage D: u = h @ uw + ub ; 16 waves x 1 tile (pinned fD) ====
        {
            f32x4 d0 = {bD, bD, bD, bD};
            f32x4 d1 = {0.f, 0.f, 0.f, 0.f};
            #pragma unroll
            for (int k = 0; k < 8; k += 2) {
                short8 a0 = *(const short8*)&hsb[lr * 264 + k * 32 + q * 8];
                short8 a1 = *(const short8*)&hsb[lr * 264 + (k + 1) * 32 + q * 8];
                d0 = __builtin_amdgcn_mfma_f32_16x16x32_bf16(a0, fD[k],     d0, 0, 0, 0);
                d1 = __builtin_amdgcn_mfma_f32_16x16x32_bf16(a1, fD[k + 1], d1, 0, 0, 0);
            }
            d0 += d1;
            if (q < 2) {
                const int col = wv * 16 + lc;
                #pragma unroll
                for (int r = 0; r < 4; ++r)
                    uu[(q * 4 + r) * 260 + col] = d0[r];
            }
        }
        __syncthreads();

        // ==== LN2 stats + cmb (waves 0..7, row = wv); wave 8 copies xs rows 0,1 for t+1 ====
        if (wv < 8) {
            const int r = wv;
            float4 u4 = *(const float4*)&uu[r * 260 + lane * 4];
            us4 h4 = *(const us4*)&hsb[r * 264 + lane * 4];
            float4 bw4 = *(const float4*)&s_bw[lane * 4];
            float s0 = u4.x + u4.y + u4.z + u4.w;
            float s1 = u4.x * u4.x + u4.y * u4.y + u4.z * u4.z + u4.w * u4.w;
            float s2 = bf2f(h4[0]) * bw4.x + bf2f(h4[1]) * bw4.y + bf2f(h4[2]) * bw4.z + bf2f(h4[3]) * bw4.w;
            #pragma unroll
            for (int mk = 1; mk < 64; mk <<= 1) {
                s0 += __shfl_xor(s0, mk);
                s1 += __shfl_xor(s1, mk);
                s2 += __shfl_xor(s2, mk);
            }
            float mean = s0 * (1.0f / UU);
            float var = s1 * (1.0f / UU) - mean * mean;
            float rstd = rsqrtf(var + LN_EPS);
            if (lane == 0) ects[r] = s2;
            float4 g4 = *(const float4*)&s_g2[lane * 4];
            float4 bb4 = *(const float4*)&s_b2[lane * 4];
            us4 o;
            o[0] = f2bf((u4.x - mean) * rstd * g4.x + bb4.x);
            o[1] = f2bf((u4.y - mean) * rstd * g4.y + bb4.y);
            o[2] = f2bf((u4.z - mean) * rstd * g4.z + bb4.z);
            o[3] = f2bf((u4.w - mean) * rstd * g4.w + bb4.w);
            *(us4*)&cmb[r * 264 + lane * 4] = o;
        } else if (wv == 8) {
            // xs(t+1) rows 0,1 == xs(t) rows 1,2 (identical LN inputs) -> plain copy
            #pragma unroll
            for (int i = 0; i < 3; ++i) {
                int idx = lane + (i << 6);
                if (idx < 176) {
                    int rr = idx / 22;
                    int cc = idx - rr * 22;
                    xn[rr * 72 + cc] = xc[rr * 72 + 11 + cc];
                }
            }
        }
        __syncthreads();

        // ==== stage F: g = tanh(comb @ dw1 + ect*w257 + db1) ; 16 waves x 2 tiles,
        //      A-frags read once (fa[8]); B streamed.  stage G fused (pinned fG) ====
        {
            short8 fa[8];
            #pragma unroll
            for (int k = 0; k < 8; ++k)
                fa[k] = *(const short8*)&cmb[lr * 264 + k * 32 + q * 8];
            float er0 = ects[(q * 4 + 0) & 7];
            float er1 = ects[(q * 4 + 1) & 7];
            float er2 = ects[(q * 4 + 2) & 7];
            float er3 = ects[(q * 4 + 3) & 7];
            #pragma unroll
            for (int tt = 0; tt < 2; ++tt) {
                const float bias = (tt == 0) ? bF0 : bF1;
                const float wc   = (tt == 0) ? wE0 : wE1;
                f32x4 ac0 = {bias, bias, bias, bias};
                f32x4 ac1 = {0.f, 0.f, 0.f, 0.f};
                #pragma unroll 4
                for (int k = 0; k < 8; ++k) {
                    short8 bf = *(const short8*)&pool[O_DW1 + ((((2 * wv + tt) << 3) + k) << 9) + (lane << 3)];
                    if (k & 1) ac1 = __builtin_amdgcn_mfma_f32_16x16x32_bf16(fa[k], bf, ac1, 0, 0, 0);
                    else       ac0 = __builtin_amdgcn_mfma_f32_16x16x32_bf16(fa[k], bf, ac0, 0, 0, 0);
                }
                ac0 += ac1;
                if (q < 2) {
                    const int col = (2 * wv + tt) * 16 + lc;
                    gsb[(q * 4 + 0) * 520 + col] = f2bf(ftanh(ac0[0] + er0 * wc));
                    gsb[(q * 4 + 1) * 520 + col] = f2bf(ftanh(ac0[1] + er1 * wc));
                    gsb[(q * 4 + 2) * 520 + col] = f2bf(ftanh(ac0[2] + er2 * wc));
                    gsb[(q * 4 + 3) * 520 + col] = f2bf(ftanh(ac0[3] + er3 * wc));
                }
            }
            // G: wave wv owns kt=wv; gsb cols [32wv,32wv+32) were written by this wave
            f32x4 ag = {0.f, 0.f, 0.f, 0.f};
            short8 ga = *(const short8*)&gsb[lr * 520 + wv * 32 + q * 8];
            ag = __builtin_amdgcn_mfma_f32_16x16x32_bf16(ga, fG, ag, 0, 0, 0);
            if (q < 2 && lc < 8) {
                #pragma unroll
                for (int r = 0; r < 4; ++r)
                    red2[wv][q * 4 + r][lc] = ag[r];
            }
        }
        __syncthreads();

        // ==== finalize (wave 0): y, out, xs(t+1) row 2 (prefetched inputs, shfl-gathered y) ====
        if (wv == 0) {
            const int r = lane >> 3, f = lane & 7;
            const int b = b0 + r;
            float a0  = red2[0][r][f],  a1  = red2[1][r][f],  a2  = red2[2][r][f],  a3  = red2[3][r][f];
            float a4  = red2[4][r][f],  a5  = red2[5][r][f],  a6  = red2[6][r][f],  a7  = red2[7][r][f];
            float a8  = red2[8][r][f],  a9  = red2[9][r][f],  a10 = red2[10][r][f], a11 = red2[11][r][f];
            float a12 = red2[12][r][f], a13 = red2[13][r][f], a14 = red2[14][r][f], a15 = red2[15][r][f];
            float y = db2r + ((((a0 + a1) + (a2 + a3)) + ((a4 + a5) + (a6 + a7)))
                            + (((a8 + a9) + (a10 + a11)) + ((a12 + a13) + (a14 + a15))));
            if (f == fx0) y = pF0;
            if (f == fx1) y = pF1;
            out[((size_t)(f * 1024 + b)) * NSTEP + t] = y;
            // gather this step's y row for the row-2 LN (lane rr<8 uses lanes rr*8..rr*8+7)
            float w8[8];
            #pragma unroll
            for (int ff = 0; ff < 8; ++ff) w8[ff] = __shfl(y, ((lane & 7) << 3) + ff);
            if (lane < 8) {
                float v[DD];
                v[0] = pLd; v[1] = pLd; v[2] = pLd - pPrev;
                #pragma unroll
                for (int ff = 0; ff < NOUT; ++ff) v[3 + ff] = w8[ff];
                float m = 0.f;
                #pragma unroll
                for (int j = 0; j < DD; ++j) m += v[j];
                m *= (1.0f / DD);
                float var = 0.f;
                #pragma unroll
                for (int j = 0; j < DD; ++j) { float d = v[j] - m; var += d * d; }
                var *= (1.0f / DD);
                float rs = rsqrtf(var + LN_EPS);
                #pragma unroll
                for (int j = 0; j < DD; ++j)
                    xn[lane * 72 + 22 + j] = f2bf((v[j] - m) * rs * s_g1[j] + s_b1[j]);
            }
        }
        __syncthreads();
    }
}

// ================= fallback (fp32 VALU, R3-proven) =================
#define MROW 4
#define NTF 1024
__global__ __launch_bounds__(NTF)
void solver_fb(const float* __restrict__ inputs,
               const float* __restrict__ g1v, const float* __restrict__ b1v,
               const float* __restrict__ ew1, const float* __restrict__ eb1,
               const float* __restrict__ ew2, const float* __restrict__ eb2,
               const float* __restrict__ uw,  const float* __restrict__ ub,
               const float* __restrict__ g2v, const float* __restrict__ b2v,
               const float* __restrict__ bww,
               const float* __restrict__ dw1, const float* __restrict__ db1,
               const float* __restrict__ dw2, const float* __restrict__ db2,
               const int* __restrict__ fixv,
               float* __restrict__ out)
{
    __shared__ float x33[MROW][K1];
    __shared__ float h1s[MROW * H2];
    __shared__ float hs[MROW * UU];
    __shared__ float combs[MROW][UU + 1];
    __shared__ float gs[MROW * H2];
    __shared__ float win[MROW][LBK][NOUT];
    __shared__ float redf[8192];
    __shared__ float red2[32][32];
    __shared__ float wred[16][3];
    __shared__ float rowstat[MROW][3];
    __shared__ float ynew[MROW][NOUT];
    float2* redf2 = reinterpret_cast<float2*>(redf);
    const int tid = threadIdx.x;
    const int b0 = blockIdx.x * MROW;
    const int fx0 = fixv[0], fx1 = fixv[1];
    if (tid < MROW * LBK * NOUT) {
        int r = tid / (LBK * NOUT);
        int rem = tid % (LBK * NOUT);
        int p = rem / NOUT, f = rem % NOUT;
        win[r][p][f] = inputs[((size_t)(b0 + r) * S_LEN + p) * FIN + 1 + f];
    }
    __syncthreads();
    for (int t = 0; t < NSTEP; ++t) {
        const int i = t + LBK;
        if (tid < MROW * LBK) {
            int r = tid / LBK, p = tid % LBK;
            int b = b0 + r;
            int tt = i - LBK + p;
            float ld = inputs[((size_t)b * S_LEN + tt) * FIN];
            float df = (tt > 0) ? ld - inputs[((size_t)b * S_LEN + tt - 1) * FIN] : 0.f;
            float v[DD];
            v[0] = ld; v[1] = ld; v[2] = df;
            #pragma unroll
            for (int f = 0; f < NOUT; ++f) v[3 + f] = win[r][p][f];
            float m = 0.f;
            #pragma unroll
            for (int j = 0; j < DD; ++j) m += v[j];
            m *= (1.0f / DD);
            float var = 0.f;
            #pragma unroll
            for (int j = 0; j < DD; ++j) { float d = v[j] - m; var += d * d; }
            var *= (1.0f / DD);
            float rs = rsqrtf(var + LN_EPS);
            #pragma unroll
            for (int j = 0; j < DD; ++j)
                x33[r][p * DD + j] = (v[j] - m) * rs * g1v[j] + b1v[j];
        }
        __syncthreads();
        {
            int cc = tid & 255, c0 = cc * 2;
            int ks = tid >> 8;
            int kbeg = ks * 8;
            int kend = (ks == 3) ? K1 : kbeg + 8;
            float2 acc[MROW];
            #pragma unroll
            for (int r = 0; r < MROW; ++r) acc[r] = make_float2(0.f, 0.f);
            for (int k = kbeg; k < kend; ++k) {
                float2 w = *reinterpret_cast<const float2*>(ew1 + (size_t)k * H2 + c0);
                #pragma unroll
                for (int r = 0; r < MROW; ++r) {
                    float xv = x33[r][k];
                    acc[r].x += xv * w.x; acc[r].y += xv * w.y;
                }
            }
            #pragma unroll
            for (int r = 0; r < MROW; ++r) redf2[ks * 1024 + r * 256 + cc] = acc[r];
        }
        __syncthreads();
        {
            #pragma unroll
            for (int jj = 0; jj < 2; ++jj) {
                int o = tid + jj * 1024;
                float v = redf[o] + redf[2048 + o] + redf[4096 + o] + redf[6144 + o] + eb1[o & 511];
                h1s[o] = tanhf(v);
            }
        }
        __syncthreads();
        {
            int cc = tid & 127, c0 = cc * 2;
            int ks = tid >> 7;
            int kbeg = ks * 64;
            float2 acc[MROW];
            #pragma unroll
            for (int r = 0; r < MROW; ++r) acc[r] = make_float2(0.f, 0.f);
            #pragma unroll 8
            for (int k = kbeg; k < kbeg + 64; ++k) {
                float2 w = *reinterpret_cast<const float2*>(ew2 + (size_t)k * UU + c0);
                #pragma unroll
                for (int r = 0; r < MROW; ++r) {
                    float hv = h1s[r * H2 + k];
                    acc[r].x += hv * w.x; acc[r].y += hv * w.y;
                }
            }
            #pragma unroll
            for (int r = 0; r < MROW; ++r) redf2[ks * 512 + r * 128 + cc] = acc[r];
        }
        __syncthreads();
        {
            int o = tid;
            float v = eb2[o & 255];
            #pragma unroll
            for (int ks = 0; ks < 8; ++ks) v += redf[ks * 1024 + o];
            hs[o] = v;
        }
        __syncthreads();
        {
            int cc = tid & 127, c0 = cc * 2;
            int ks = tid >> 7;
            int kbeg = ks * 32;
            float2 acc[MROW];
            #pragma unroll
            for (int r = 0; r < MROW; ++r) acc[r] = make_float2(0.f, 0.f);
            #pragma unroll 8
            for (int k = kbeg; k < kbeg + 32; ++k) {
                float2 w = *reinterpret_cast<const float2*>(uw + (size_t)k * UU + c0);
                #pragma unroll
                for (int r = 0; r < MROW; ++r) {
                    float hv = hs[r * UU + k];
                    acc[r].x += hv * w.x; acc[r].y += hv * w.y;
                }
            }
            #pragma unroll
            for (int r = 0; r < MROW; ++r) redf2[ks * 512 + r * 128 + cc] = acc[r];
        }
        __syncthreads();
        {
            int o = tid, r = o >> 8, c = o & 255;
            float v = ub[c];
            #pragma unroll
            for (int ks = 0; ks < 8; ++ks) v += redf[ks * 1024 + o];
            combs[r][c] = v;
        }
        __syncthreads();
        {
            int r = tid >> 8, c = tid & 255;
            float u = combs[r][c];
            float hb = hs[r * UU + c] * bww[c];
            float s0 = u, s1 = u * u, s2 = hb;
            #pragma unroll
            for (int mk = 1; mk < 64; mk <<= 1) {
                s0 += __shfl_xor(s0, mk);
                s1 += __shfl_xor(s1, mk);
                s2 += __shfl_xor(s2, mk);
            }
            if ((tid & 63) == 0) {
                int w = tid >> 6;
                wred[w][0] = s0; wred[w][1] = s1; wred[w][2] = s2;
            }
        }
        __syncthreads();
        if (tid < MROW) {
            int r = tid;
            float t0 = 0.f, t1 = 0.f, t2 = 0.f;
            #pragma unroll
            for (int w = 4 * r; w < 4 * r + 4; ++w) { t0 += wred[w][0]; t1 += wred[w][1]; t2 += wred[w][2]; }
            float mean = t0 * (1.0f / UU);
            float var = t1 * (1.0f / UU) - mean * mean;
            rowstat[r][0] = mean; rowstat[r][1] = rsqrtf(var + LN_EPS); rowstat[r][2] = t2;
        }
        __syncthreads();
        {
            int r = tid >> 8, c = tid & 255;
            float u = combs[r][c];
            combs[r][c] = (u - rowstat[r][0]) * rowstat[r][1] * g2v[c] + b2v[c];
            if (tid < MROW) combs[tid][UU] = rowstat[tid][2];
        }
        __syncthreads();
        {
            int cc = tid & 255, c0 = cc * 2;
            int ks = tid >> 8;
            int kbeg = ks * 64;
            int kend = (ks == 3) ? (UU + 1) : kbeg + 64;
            float2 acc[MROW];
            #pragma unroll
            for (int r = 0; r < MROW; ++r) acc[r] = make_float2(0.f, 0.f);
            #pragma unroll 8
            for (int k = kbeg; k < kend; ++k) {
                float2 w = *reinterpret_cast<const float2*>(dw1 + (size_t)k * H2 + c0);
                #pragma unroll
                for (int r = 0; r < MROW; ++r) {
                    float cv = combs[r][k];
                    acc[r].x += cv * w.x; acc[r].y += cv * w.y;
                }
            }
            #pragma unroll
            for (int r = 0; r < MROW; ++r) redf2[ks * 1024 + r * 256 + cc] = acc[r];
        }
        __syncthreads();
        {
            #pragma unroll
            for (int jj = 0; jj < 2; ++jj) {
                int o = tid + jj * 1024;
                float v = redf[o] + redf[2048 + o] + redf[4096 + o] + redf[6144 + o] + db1[o & 511];
                gs[o] = tanhf(v);
            }
        }
        __syncthreads();
        {
            int o = tid & 31, kc = tid >> 5;
            int r = o >> 3, f = o & 7;
            int kbeg = kc * 16;
            float p = 0.f;
            #pragma unroll 4
            for (int k = kbeg; k < kbeg + 16; ++k)
                p += gs[r * H2 + k] * dw2[(size_t)k * NOUT + f];
            red2[kc][o] = p;
        }
        __syncthreads();
        if (tid < 32) {
            int o = tid, r = o >> 3, f = o & 7;
            int b = b0 + r;
            float y = db2[f];
            #pragma unroll
            for (int kc = 0; kc < 32; ++kc) y += red2[kc][o];
            if (f == fx0) y = inputs[((size_t)b * S_LEN + i + 1) * FIN + 1 + fx0];
            if (f == fx1) y = inputs[((size_t)b * S_LEN + i + 1) * FIN + 1 + fx1];
            ynew[r][f] = y;
            out[((size_t)(f * 1024 + b)) * NSTEP + t] = y;
        }
        __syncthreads();
        {
            float wshift = 0.f;
            int sr = 0, sp = 0, sf = 0;
            bool doshift = tid < MROW * LBK * NOUT;
            if (doshift) {
                sr = tid / (LBK * NOUT);
                int rem = tid % (LBK * NOUT);
                sp = rem / NOUT; sf = rem % NOUT;
                wshift = (sp < LBK - 1) ? win[sr][sp + 1][sf] : ynew[sr][sf];
            }
            __syncthreads();
            if (doshift) win[sr][sp][sf] = wshift;
        }
        __syncthreads();
    }
}

extern "C" void kernel_launch(void* const* d_in, const int* in_sizes, int n_in,
                              void* d_out, int out_size, void* d_ws, size_t ws_size,
                              hipStream_t stream) {
    (void)in_sizes; (void)n_in; (void)out_size;
    const bool use_mfma = (d_ws != nullptr) && (ws_size >= (size_t)W_TOT * sizeof(unsigned short));
    if (use_mfma) {
        unsigned short* pool = (unsigned short*)d_ws;
        convw<<<(W_TOT + 255) / 256, 256, 0, stream>>>(
            (const float*)d_in[3], (const float*)d_in[5], (const float*)d_in[7],
            (const float*)d_in[12], (const float*)d_in[14], pool);
        solver<<<GRID, 1024, 0, stream>>>(
            (const float*)d_in[0], pool,
            (const float*)d_in[1], (const float*)d_in[2],
            (const float*)d_in[4], (const float*)d_in[6],
            (const float*)d_in[8], (const float*)d_in[9],
            (const float*)d_in[10], (const float*)d_in[11],
            (const float*)d_in[12], (const float*)d_in[13],
            (const float*)d_in[15], (const int*)d_in[16],
            (float*)d_out);
    } else {
        solver_fb<<<256, NTF, 0, stream>>>(
            (const float*)d_in[0],
            (const float*)d_in[1], (const float*)d_in[2],
            (const float*)d_in[3], (const float*)d_in[4],
            (const float*)d_in[5], (const float*)d_in[6],
            (const float*)d_in[7], (const float*)d_in[8],
            (const float*)d_in[9], (const float*)d_in[10],
            (const float*)d_in[11],
            (const float*)d_in[12], (const float*)d_in[13],
            (const float*)d_in[14], (const float*)d_in[15],
            (const int*)d_in[16],
            (float*)d_out);
    }
}

// Round 5
// 43684.299 us; speedup vs baseline: 12.4030x; 12.4030x over previous
//
#include <hip/hip_runtime.h>
#include <math.h>

#define S_LEN 2048
#define FIN 9
#define NOUT 8
#define LBK 3
#define DD 11
#define K1 33
#define H2 512
#define UU 256
#define NSTEP 2044
#define MR 8
#define GRID 128
#define LN_EPS 1e-3f

typedef __attribute__((ext_vector_type(8))) short short8;
typedef __attribute__((ext_vector_type(4))) float f32x4;
typedef __attribute__((ext_vector_type(4))) unsigned short us4;

// ---- packed B-fragment pool (bf16): tile (nt,kt): 64 lanes x 8 bf16,
// elem = B[k][n], k = kt*32 + (lane>>4)*8 + j, n = nt*16 + (lane&15)
#define F_EW1 (32 * 2 * 512)
#define F_EW2 (16 * 16 * 512)
#define F_UW  (16 * 8 * 512)
#define F_DW1 (32 * 8 * 512)
#define F_DW2 (1 * 16 * 512)
#define O_EW1 0
#define O_EW2 (O_EW1 + F_EW1)
#define O_UW  (O_EW2 + F_EW2)
#define O_DW1 (O_UW + F_UW)
#define O_DW2 (O_DW1 + F_DW1)
#define W_TOT (O_DW2 + F_DW2)   // 368640 elems = 737280 B

__device__ __forceinline__ unsigned short f2bf(float f) {
    unsigned u = __float_as_uint(f);
    u = (u + 0x7fffu + ((u >> 16) & 1u)) >> 16;
    return (unsigned short)u;
}
__device__ __forceinline__ float bf2f(unsigned short u) {
    return __uint_as_float(((unsigned)u) << 16);
}
__device__ __forceinline__ float ftanh(float x) {
    float ax = fabsf(x);
    float e = __expf(-2.0f * ax);
    float r = __fdividef(1.0f - e, 1.0f + e);
    return copysignf(r, x);
}

extern "C" __global__ void convw(const float* __restrict__ ew1, const float* __restrict__ ew2,
                                 const float* __restrict__ uw,  const float* __restrict__ dw1,
                                 const float* __restrict__ dw2, unsigned short* __restrict__ o)
{
    int i = blockIdx.x * blockDim.x + threadIdx.x;
    if (i >= W_TOT) return;
    int p, KT, K, N; const float* W;
    if (i < O_EW2)      { p = i - O_EW1; KT = 2;  K = 33;  N = 512; W = ew1; }
    else if (i < O_UW)  { p = i - O_EW2; KT = 16; K = 512; N = 256; W = ew2; }
    else if (i < O_DW1) { p = i - O_UW;  KT = 8;  K = 256; N = 256; W = uw;  }
    else if (i < O_DW2) { p = i - O_DW1; KT = 8;  K = 256; N = 512; W = dw1; }
    else                { p = i - O_DW2; KT = 16; K = 512; N = 8;   W = dw2; }
    int frag = p >> 9, rem = p & 511;
    int ln = rem >> 3, j = rem & 7;
    int nt = frag / KT, kt = frag % KT;
    int k = kt * 32 + (ln >> 4) * 8 + j;
    int n = nt * 16 + (ln & 15);
    float v = 0.f;
    if (k < K && n < N) v = W[k * N + n];
    o[i] = f2bf(v);
}

extern "C" __global__ void __launch_bounds__(1024, 4)
solver(const float* __restrict__ inputs,
       const unsigned short* __restrict__ pool,
       const float* __restrict__ g1v, const float* __restrict__ b1v,
       const float* __restrict__ eb1, const float* __restrict__ eb2,
       const float* __restrict__ ub,  const float* __restrict__ g2v,
       const float* __restrict__ b2v, const float* __restrict__ bww,
       const float* __restrict__ dw1, const float* __restrict__ db1,
       const float* __restrict__ db2, const int* __restrict__ fixv,
       float* __restrict__ out)
{
    __shared__ unsigned short xs[2][MR * 72];   // LN1 out, double-buffered (33 used, zeros to 64)
    __shared__ unsigned short h1[MR * 520];     // tanh(enc1)
    __shared__ unsigned short hsb[MR * 264];    // enc2 out
    __shared__ __align__(16) float uu[MR * 260];// upd out fp32
    __shared__ unsigned short cmb[MR * 264];    // LN2 out bf16
    __shared__ unsigned short gsb[MR * 520];    // tanh(dec1)
    __shared__ float red2[16][MR][9];           // G partials (16 waves)
    __shared__ float ects[MR];
    __shared__ float s_g1[DD], s_b1[DD];
    __shared__ __align__(16) float s_g2[256], s_b2[256], s_bw[256];

    const int tid = threadIdx.x;
    const int lane = tid & 63;
    const int wv = tid >> 6;      // 0..15
    const int q = lane >> 4;      // 0..3
    const int lc = lane & 15;     // tile col / output col
    const int lr = lc & 7;        // A-row (rows 8..15 duplicate 0..7)
    const int b0 = blockIdx.x * MR;
    const int fx0 = fixv[0], fx1 = fixv[1];

    // ---- preamble ----
    for (int z = tid; z < 2 * MR * 72; z += 1024) (&xs[0][0])[z] = 0;
    for (int z = tid; z < 256; z += 1024) { s_g2[z] = g2v[z]; s_b2[z] = b2v[z]; s_bw[z] = bww[z]; }
    if (tid >= 256 && tid < 256 + DD) { s_g1[tid - 256] = g1v[tid - 256]; s_b1[tid - 256] = b1v[tid - 256]; }

    // ---- pinned step-invariant fragments (baseline budget: 36 regs) ----
    short8 fD[8];
    #pragma unroll
    for (int kt = 0; kt < 8; ++kt)
        fD[kt] = *(const short8*)&pool[O_UW + (((wv << 3) + kt) << 9) + (lane << 3)];
    short8 fG = *(const short8*)&pool[O_DW2 + (wv << 9) + (lane << 3)];

    // per-wave bias/scale scalars
    const float bB0 = eb1[(2 * wv) * 16 + lc];
    const float bB1 = eb1[(2 * wv + 1) * 16 + lc];
    const float bC  = eb2[wv * 16 + lc];
    const float bD  = ub[wv * 16 + lc];
    const float bF0 = db1[(2 * wv) * 16 + lc];
    const float bF1 = db1[(2 * wv + 1) * 16 + lc];
    const float wE0 = dw1[256 * 512 + (2 * wv) * 16 + lc];
    const float wE1 = dw1[256 * 512 + (2 * wv + 1) * 16 + lc];
    const float db2r = db2[lane & 7];

    __syncthreads();

    // ---- stage A for t=0 (window rows straight from inputs) ----
    if (tid < MR * LBK) {
        int r = tid / LBK, p = tid % LBK;
        int b = b0 + r;
        float ld = inputs[((size_t)b * S_LEN + p) * FIN];
        float df = (p > 0) ? ld - inputs[((size_t)b * S_LEN + p - 1) * FIN] : 0.f;
        float v[DD];
        v[0] = ld; v[1] = ld; v[2] = df;
        #pragma unroll
        for (int f = 0; f < NOUT; ++f) v[3 + f] = inputs[((size_t)b * S_LEN + p) * FIN + 1 + f];
        float m = 0.f;
        #pragma unroll
        for (int j = 0; j < DD; ++j) m += v[j];
        m *= (1.0f / DD);
        float var = 0.f;
        #pragma unroll
        for (int j = 0; j < DD; ++j) { float d = v[j] - m; var += d * d; }
        var *= (1.0f / DD);
        float rs = rsqrtf(var + LN_EPS);
        #pragma unroll
        for (int j = 0; j < DD; ++j)
            xs[0][r * 72 + p * DD + j] = f2bf((v[j] - m) * rs * s_g1[j] + s_b1[j]);
    }
    __syncthreads();

    for (int t = 0; t < NSTEP; ++t) {
        unsigned short* xc = &xs[t & 1][0];
        unsigned short* xn = &xs[(t & 1) ^ 1][0];

        // ---- wave 0: prefetch finalize inputs for THIS step; latency hides under B..F ----
        float pLd = 0.f, pPrev = 0.f, pF0 = 0.f, pF1 = 0.f;
        if (wv == 0) {
            const int r8 = lane & 7;
            const int rr = lane >> 3;
            pLd   = inputs[((size_t)(b0 + r8) * S_LEN + t + 3) * FIN];
            pPrev = inputs[((size_t)(b0 + r8) * S_LEN + t + 2) * FIN];
            pF0   = inputs[((size_t)(b0 + rr) * S_LEN + t + 4) * FIN + 1 + fx0];
            pF1   = inputs[((size_t)(b0 + rr) * S_LEN + t + 4) * FIN + 1 + fx1];
        }

        // ==== stage B: h1 = tanh(x @ ew1 + eb1), 33(pad64)->512 ; 16 waves x 2 tiles (streamed) ====
        {
            short8 a0 = *(const short8*)&xc[lr * 72 + q * 8];
            short8 a1 = *(const short8*)&xc[lr * 72 + 32 + q * 8];
            short8 b00 = *(const short8*)&pool[O_EW1 + ((((2 * wv)     << 1) + 0) << 9) + (lane << 3)];
            short8 b01 = *(const short8*)&pool[O_EW1 + ((((2 * wv)     << 1) + 1) << 9) + (lane << 3)];
            short8 b10 = *(const short8*)&pool[O_EW1 + ((((2 * wv + 1) << 1) + 0) << 9) + (lane << 3)];
            short8 b11 = *(const short8*)&pool[O_EW1 + ((((2 * wv + 1) << 1) + 1) << 9) + (lane << 3)];
            f32x4 acc0 = {bB0, bB0, bB0, bB0};
            f32x4 acc1 = {bB1, bB1, bB1, bB1};
            acc0 = __builtin_amdgcn_mfma_f32_16x16x32_bf16(a0, b00, acc0, 0, 0, 0);
            acc0 = __builtin_amdgcn_mfma_f32_16x16x32_bf16(a1, b01, acc0, 0, 0, 0);
            acc1 = __builtin_amdgcn_mfma_f32_16x16x32_bf16(a0, b10, acc1, 0, 0, 0);
            acc1 = __builtin_amdgcn_mfma_f32_16x16x32_bf16(a1, b11, acc1, 0, 0, 0);
            if (q < 2) {
                const int c0 = (2 * wv) * 16 + lc, c1 = (2 * wv + 1) * 16 + lc;
                #pragma unroll
                for (int r = 0; r < 4; ++r) {
                    h1[(q * 4 + r) * 520 + c0] = f2bf(ftanh(acc0[r]));
                    h1[(q * 4 + r) * 520 + c1] = f2bf(ftanh(acc1[r]));
                }
            }
        }
        __syncthreads();

        // ==== stage C: h = h1 @ ew2 + eb2, 512->256 ; 16 waves x 1 tile (streamed B) ====
        {
            f32x4 c0 = {bC, bC, bC, bC};
            f32x4 c1 = {0.f, 0.f, 0.f, 0.f};
            #pragma unroll 4
            for (int k = 0; k < 16; ++k) {
                short8 av = *(const short8*)&h1[lr * 520 + k * 32 + q * 8];
                short8 bf = *(const short8*)&pool[O_EW2 + (((wv << 4) + k) << 9) + (lane << 3)];
                if (k & 1) c1 = __builtin_amdgcn_mfma_f32_16x16x32_bf16(av, bf, c1, 0, 0, 0);
                else       c0 = __builtin_amdgcn_mfma_f32_16x16x32_bf16(av, bf, c0, 0, 0, 0);
            }
            c0 += c1;
            if (q < 2) {
                const int col = wv * 16 + lc;
                #pragma unroll
                for (int r = 0; r < 4; ++r)
                    hsb[(q * 4 + r) * 264 + col] = f2bf(c0[r]);
            }
        }
        __syncthreads();

        // ==== stage D: u = h @ uw + ub ; 16 waves x 1 tile (pinned fD) ====
        {
            f32x4 d0 = {bD, bD, bD, bD};
            f32x4 d1 = {0.f, 0.f, 0.f, 0.f};
            #pragma unroll
            for (int k = 0; k < 8; k += 2) {
                short8 a0 = *(const short8*)&hsb[lr * 264 + k * 32 + q * 8];
                short8 a1 = *(const short8*)&hsb[lr * 264 + (k + 1) * 32 + q * 8];
                d0 = __builtin_amdgcn_mfma_f32_16x16x32_bf16(a0, fD[k],     d0, 0, 0, 0);
                d1 = __builtin_amdgcn_mfma_f32_16x16x32_bf16(a1, fD[k + 1], d1, 0, 0, 0);
            }
            d0 += d1;
            if (q < 2) {
                const int col = wv * 16 + lc;
                #pragma unroll
                for (int r = 0; r < 4; ++r)
                    uu[(q * 4 + r) * 260 + col] = d0[r];
            }
        }
        __syncthreads();

        // ==== LN2 stats + cmb (waves 0..7, row = wv); wave 8 copies xs rows 0,1 for t+1 ====
        if (wv < 8) {
            const int r = wv;
            float4 u4 = *(const float4*)&uu[r * 260 + lane * 4];
            us4 h4 = *(const us4*)&hsb[r * 264 + lane * 4];
            float4 bw4 = *(const float4*)&s_bw[lane * 4];
            float s0 = u4.x + u4.y + u4.z + u4.w;
            float s1 = u4.x * u4.x + u4.y * u4.y + u4.z * u4.z + u4.w * u4.w;
            float s2 = bf2f(h4[0]) * bw4.x + bf2f(h4[1]) * bw4.y + bf2f(h4[2]) * bw4.z + bf2f(h4[3]) * bw4.w;
            #pragma unroll
            for (int mk = 1; mk < 64; mk <<= 1) {
                s0 += __shfl_xor(s0, mk);
                s1 += __shfl_xor(s1, mk);
                s2 += __shfl_xor(s2, mk);
            }
            float mean = s0 * (1.0f / UU);
            float var = s1 * (1.0f / UU) - mean * mean;
            float rstd = rsqrtf(var + LN_EPS);
            if (lane == 0) ects[r] = s2;
            float4 g4 = *(const float4*)&s_g2[lane * 4];
            float4 bb4 = *(const float4*)&s_b2[lane * 4];
            us4 o;
            o[0] = f2bf((u4.x - mean) * rstd * g4.x + bb4.x);
            o[1] = f2bf((u4.y - mean) * rstd * g4.y + bb4.y);
            o[2] = f2bf((u4.z - mean) * rstd * g4.z + bb4.z);
            o[3] = f2bf((u4.w - mean) * rstd * g4.w + bb4.w);
            *(us4*)&cmb[r * 264 + lane * 4] = o;
        } else if (wv == 8) {
            // xs(t+1) rows 0,1 == xs(t) rows 1,2 (identical LN inputs) -> plain copy
            #pragma unroll
            for (int i = 0; i < 3; ++i) {
                int idx = lane + (i << 6);
                if (idx < 176) {
                    int rr = idx / 22;
                    int cc = idx - rr * 22;
                    xn[rr * 72 + cc] = xc[rr * 72 + 11 + cc];
                }
            }
        }
        __syncthreads();

        // ==== stage F: g = tanh(comb @ dw1 + ect*w257 + db1) ; 16 waves x 2 tiles,
        //      A-frags read once (fa[8], FULL unroll => registers, rule #20); B streamed.
        //      stage G fused (pinned fG) ====
        {
            short8 fa[8];
            #pragma unroll
            for (int k = 0; k < 8; ++k)
                fa[k] = *(const short8*)&cmb[lr * 264 + k * 32 + q * 8];
            float er0 = ects[(q * 4 + 0) & 7];
            float er1 = ects[(q * 4 + 1) & 7];
            float er2 = ects[(q * 4 + 2) & 7];
            float er3 = ects[(q * 4 + 3) & 7];
            #pragma unroll
            for (int tt = 0; tt < 2; ++tt) {
                const float bias = (tt == 0) ? bF0 : bF1;
                const float wc   = (tt == 0) ? wE0 : wE1;
                f32x4 ac0 = {bias, bias, bias, bias};
                f32x4 ac1 = {0.f, 0.f, 0.f, 0.f};
                #pragma unroll
                for (int k = 0; k < 8; ++k) {
                    short8 bf = *(const short8*)&pool[O_DW1 + ((((2 * wv + tt) << 3) + k) << 9) + (lane << 3)];
                    if (k & 1) ac1 = __builtin_amdgcn_mfma_f32_16x16x32_bf16(fa[k], bf, ac1, 0, 0, 0);
                    else       ac0 = __builtin_amdgcn_mfma_f32_16x16x32_bf16(fa[k], bf, ac0, 0, 0, 0);
                }
                ac0 += ac1;
                if (q < 2) {
                    const int col = (2 * wv + tt) * 16 + lc;
                    gsb[(q * 4 + 0) * 520 + col] = f2bf(ftanh(ac0[0] + er0 * wc));
                    gsb[(q * 4 + 1) * 520 + col] = f2bf(ftanh(ac0[1] + er1 * wc));
                    gsb[(q * 4 + 2) * 520 + col] = f2bf(ftanh(ac0[2] + er2 * wc));
                    gsb[(q * 4 + 3) * 520 + col] = f2bf(ftanh(ac0[3] + er3 * wc));
                }
            }
            // G: wave wv owns kt=wv; gsb cols [32wv,32wv+32) were written by this wave
            f32x4 ag = {0.f, 0.f, 0.f, 0.f};
            short8 ga = *(const short8*)&gsb[lr * 520 + wv * 32 + q * 8];
            ag = __builtin_amdgcn_mfma_f32_16x16x32_bf16(ga, fG, ag, 0, 0, 0);
            if (q < 2 && lc < 8) {
                #pragma unroll
                for (int r = 0; r < 4; ++r)
                    red2[wv][q * 4 + r][lc] = ag[r];
            }
        }
        __syncthreads();

        // ==== finalize (wave 0): y, out, xs(t+1) row 2 (prefetched inputs, shfl-gathered y) ====
        if (wv == 0) {
            const int r = lane >> 3, f = lane & 7;
            const int b = b0 + r;
            float a0  = red2[0][r][f],  a1  = red2[1][r][f],  a2  = red2[2][r][f],  a3  = red2[3][r][f];
            float a4  = red2[4][r][f],  a5  = red2[5][r][f],  a6  = red2[6][r][f],  a7  = red2[7][r][f];
            float a8  = red2[8][r][f],  a9  = red2[9][r][f],  a10 = red2[10][r][f], a11 = red2[11][r][f];
            float a12 = red2[12][r][f], a13 = red2[13][r][f], a14 = red2[14][r][f], a15 = red2[15][r][f];
            float y = db2r + ((((a0 + a1) + (a2 + a3)) + ((a4 + a5) + (a6 + a7)))
                            + (((a8 + a9) + (a10 + a11)) + ((a12 + a13) + (a14 + a15))));
            if (f == fx0) y = pF0;
            if (f == fx1) y = pF1;
            out[((size_t)(f * 1024 + b)) * NSTEP + t] = y;
            // gather this step's y row for the row-2 LN (lane rr<8 uses lanes rr*8..rr*8+7)
            float w8[8];
            #pragma unroll
            for (int ff = 0; ff < 8; ++ff) w8[ff] = __shfl(y, ((lane & 7) << 3) + ff);
            if (lane < 8) {
                float v[DD];
                v[0] = pLd; v[1] = pLd; v[2] = pLd - pPrev;
                #pragma unroll
                for (int ff = 0; ff < NOUT; ++ff) v[3 + ff] = w8[ff];
                float m = 0.f;
                #pragma unroll
                for (int j = 0; j < DD; ++j) m += v[j];
                m *= (1.0f / DD);
                float var = 0.f;
                #pragma unroll
                for (int j = 0; j < DD; ++j) { float d = v[j] - m; var += d * d; }
                var *= (1.0f / DD);
                float rs = rsqrtf(var + LN_EPS);
                #pragma unroll
                for (int j = 0; j < DD; ++j)
                    xn[lane * 72 + 22 + j] = f2bf((v[j] - m) * rs * s_g1[j] + s_b1[j]);
            }
        }
        __syncthreads();
    }
}

// ================= fallback (fp32 VALU, R3-proven) =================
#define MROW 4
#define NTF 1024
__global__ __launch_bounds__(NTF)
void solver_fb(const float* __restrict__ inputs,
               const float* __restrict__ g1v, const float* __restrict__ b1v,
               const float* __restrict__ ew1, const float* __restrict__ eb1,
               const float* __restrict__ ew2, const float* __restrict__ eb2,
               const float* __restrict__ uw,  const float* __restrict__ ub,
               const float* __restrict__ g2v, const float* __restrict__ b2v,
               const float* __restrict__ bww,
               const float* __restrict__ dw1, const float* __restrict__ db1,
               const float* __restrict__ dw2, const float* __restrict__ db2,
               const int* __restrict__ fixv,
               float* __restrict__ out)
{
    __shared__ float x33[MROW][K1];
    __shared__ float h1s[MROW * H2];
    __shared__ float hs[MROW * UU];
    __shared__ float combs[MROW][UU + 1];
    __shared__ float gs[MROW * H2];
    __shared__ float win[MROW][LBK][NOUT];
    __shared__ float redf[8192];
    __shared__ float red2[32][32];
    __shared__ float wred[16][3];
    __shared__ float rowstat[MROW][3];
    __shared__ float ynew[MROW][NOUT];
    float2* redf2 = reinterpret_cast<float2*>(redf);
    const int tid = threadIdx.x;
    const int b0 = blockIdx.x * MROW;
    const int fx0 = fixv[0], fx1 = fixv[1];
    if (tid < MROW * LBK * NOUT) {
        int r = tid / (LBK * NOUT);
        int rem = tid % (LBK * NOUT);
        int p = rem / NOUT, f = rem % NOUT;
        win[r][p][f] = inputs[((size_t)(b0 + r) * S_LEN + p) * FIN + 1 + f];
    }
    __syncthreads();
    for (int t = 0; t < NSTEP; ++t) {
        const int i = t + LBK;
        if (tid < MROW * LBK) {
            int r = tid / LBK, p = tid % LBK;
            int b = b0 + r;
            int tt = i - LBK + p;
            float ld = inputs[((size_t)b * S_LEN + tt) * FIN];
            float df = (tt > 0) ? ld - inputs[((size_t)b * S_LEN + tt - 1) * FIN] : 0.f;
            float v[DD];
            v[0] = ld; v[1] = ld; v[2] = df;
            #pragma unroll
            for (int f = 0; f < NOUT; ++f) v[3 + f] = win[r][p][f];
            float m = 0.f;
            #pragma unroll
            for (int j = 0; j < DD; ++j) m += v[j];
            m *= (1.0f / DD);
            float var = 0.f;
            #pragma unroll
            for (int j = 0; j < DD; ++j) { float d = v[j] - m; var += d * d; }
            var *= (1.0f / DD);
            float rs = rsqrtf(var + LN_EPS);
            #pragma unroll
            for (int j = 0; j < DD; ++j)
                x33[r][p * DD + j] = (v[j] - m) * rs * g1v[j] + b1v[j];
        }
        __syncthreads();
        {
            int cc = tid & 255, c0 = cc * 2;
            int ks = tid >> 8;
            int kbeg = ks * 8;
            int kend = (ks == 3) ? K1 : kbeg + 8;
            float2 acc[MROW];
            #pragma unroll
            for (int r = 0; r < MROW; ++r) acc[r] = make_float2(0.f, 0.f);
            for (int k = kbeg; k < kend; ++k) {
                float2 w = *reinterpret_cast<const float2*>(ew1 + (size_t)k * H2 + c0);
                #pragma unroll
                for (int r = 0; r < MROW; ++r) {
                    float xv = x33[r][k];
                    acc[r].x += xv * w.x; acc[r].y += xv * w.y;
                }
            }
            #pragma unroll
            for (int r = 0; r < MROW; ++r) redf2[ks * 1024 + r * 256 + cc] = acc[r];
        }
        __syncthreads();
        {
            #pragma unroll
            for (int jj = 0; jj < 2; ++jj) {
                int o = tid + jj * 1024;
                float v = redf[o] + redf[2048 + o] + redf[4096 + o] + redf[6144 + o] + eb1[o & 511];
                h1s[o] = tanhf(v);
            }
        }
        __syncthreads();
        {
            int cc = tid & 127, c0 = cc * 2;
            int ks = tid >> 7;
            int kbeg = ks * 64;
            float2 acc[MROW];
            #pragma unroll
            for (int r = 0; r < MROW; ++r) acc[r] = make_float2(0.f, 0.f);
            #pragma unroll 8
            for (int k = kbeg; k < kbeg + 64; ++k) {
                float2 w = *reinterpret_cast<const float2*>(ew2 + (size_t)k * UU + c0);
                #pragma unroll
                for (int r = 0; r < MROW; ++r) {
                    float hv = h1s[r * H2 + k];
                    acc[r].x += hv * w.x; acc[r].y += hv * w.y;
                }
            }
            #pragma unroll
            for (int r = 0; r < MROW; ++r) redf2[ks * 512 + r * 128 + cc] = acc[r];
        }
        __syncthreads();
        {
            int o = tid;
            float v = eb2[o & 255];
            #pragma unroll
            for (int ks = 0; ks < 8; ++ks) v += redf[ks * 1024 + o];
            hs[o] = v;
        }
        __syncthreads();
        {
            int cc = tid & 127, c0 = cc * 2;
            int ks = tid >> 7;
            int kbeg = ks * 32;
            float2 acc[MROW];
            #pragma unroll
            for (int r = 0; r < MROW; ++r) acc[r] = make_float2(0.f, 0.f);
            #pragma unroll 8
            for (int k = kbeg; k < kbeg + 32; ++k) {
                float2 w = *reinterpret_cast<const float2*>(uw + (size_t)k * UU + c0);
                #pragma unroll
                for (int r = 0; r < MROW; ++r) {
                    float hv = hs[r * UU + k];
                    acc[r].x += hv * w.x; acc[r].y += hv * w.y;
                }
            }
            #pragma unroll
            for (int r = 0; r < MROW; ++r) redf2[ks * 512 + r * 128 + cc] = acc[r];
        }
        __syncthreads();
        {
            int o = tid, r = o >> 8, c = o & 255;
            float v = ub[c];
            #pragma unroll
            for (int ks = 0; ks < 8; ++ks) v += redf[ks * 1024 + o];
            combs[r][c] = v;
        }
        __syncthreads();
        {
            int r = tid >> 8, c = tid & 255;
            float u = combs[r][c];
            float hb = hs[r * UU + c] * bww[c];
            float s0 = u, s1 = u * u, s2 = hb;
            #pragma unroll
            for (int mk = 1; mk < 64; mk <<= 1) {
                s0 += __shfl_xor(s0, mk);
                s1 += __shfl_xor(s1, mk);
                s2 += __shfl_xor(s2, mk);
            }
            if ((tid & 63) == 0) {
                int w = tid >> 6;
                wred[w][0] = s0; wred[w][1] = s1; wred[w][2] = s2;
            }
        }
        __syncthreads();
        if (tid < MROW) {
            int r = tid;
            float t0 = 0.f, t1 = 0.f, t2 = 0.f;
            #pragma unroll
            for (int w = 4 * r; w < 4 * r + 4; ++w) { t0 += wred[w][0]; t1 += wred[w][1]; t2 += wred[w][2]; }
            float mean = t0 * (1.0f / UU);
            float var = t1 * (1.0f / UU) - mean * mean;
            rowstat[r][0] = mean; rowstat[r][1] = rsqrtf(var + LN_EPS); rowstat[r][2] = t2;
        }
        __syncthreads();
        {
            int r = tid >> 8, c = tid & 255;
            float u = combs[r][c];
            combs[r][c] = (u - rowstat[r][0]) * rowstat[r][1] * g2v[c] + b2v[c];
            if (tid < MROW) combs[tid][UU] = rowstat[tid][2];
        }
        __syncthreads();
        {
            int cc = tid & 255, c0 = cc * 2;
            int ks = tid >> 8;
            int kbeg = ks * 64;
            int kend = (ks == 3) ? (UU + 1) : kbeg + 64;
            float2 acc[MROW];
            #pragma unroll
            for (int r = 0; r < MROW; ++r) acc[r] = make_float2(0.f, 0.f);
            #pragma unroll 8
            for (int k = kbeg; k < kend; ++k) {
                float2 w = *reinterpret_cast<const float2*>(dw1 + (size_t)k * H2 + c0);
                #pragma unroll
                for (int r = 0; r < MROW; ++r) {
                    float cv = combs[r][k];
                    acc[r].x += cv * w.x; acc[r].y += cv * w.y;
                }
            }
            #pragma unroll
            for (int r = 0; r < MROW; ++r) redf2[ks * 1024 + r * 256 + cc] = acc[r];
        }
        __syncthreads();
        {
            #pragma unroll
            for (int jj = 0; jj < 2; ++jj) {
                int o = tid + jj * 1024;
                float v = redf[o] + redf[2048 + o] + redf[4096 + o] + redf[6144 + o] + db1[o & 511];
                gs[o] = tanhf(v);
            }
        }
        __syncthreads();
        {
            int o = tid & 31, kc = tid >> 5;
            int r = o >> 3, f = o & 7;
            int kbeg = kc * 16;
            float p = 0.f;
            #pragma unroll 4
            for (int k = kbeg; k < kbeg + 16; ++k)
                p += gs[r * H2 + k] * dw2[(size_t)k * NOUT + f];
            red2[kc][o] = p;
        }
        __syncthreads();
        if (tid < 32) {
            int o = tid, r = o >> 3, f = o & 7;
            int b = b0 + r;
            float y = db2[f];
            #pragma unroll
            for (int kc = 0; kc < 32; ++kc) y += red2[kc][o];
            if (f == fx0) y = inputs[((size_t)b * S_LEN + i + 1) * FIN + 1 + fx0];
            if (f == fx1) y = inputs[((size_t)b * S_LEN + i + 1) * FIN + 1 + fx1];
            ynew[r][f] = y;
            out[((size_t)(f * 1024 + b)) * NSTEP + t] = y;
        }
        __syncthreads();
        {
            float wshift = 0.f;
            int sr = 0, sp = 0, sf = 0;
            bool doshift = tid < MROW * LBK * NOUT;
            if (doshift) {
                sr = tid / (LBK * NOUT);
                int rem = tid % (LBK * NOUT);
                sp = rem / NOUT; sf = rem % NOUT;
                wshift = (sp < LBK - 1) ? win[sr][sp + 1][sf] : ynew[sr][sf];
            }
            __syncthreads();
            if (doshift) win[sr][sp][sf] = wshift;
        }
        __syncthreads();
    }
}

extern "C" void kernel_launch(void* const* d_in, const int* in_sizes, int n_in,
                              void* d_out, int out_size, void* d_ws, size_t ws_size,
                              hipStream_t stream) {
    (void)in_sizes; (void)n_in; (void)out_size;
    const bool use_mfma = (d_ws != nullptr) && (ws_size >= (size_t)W_TOT * sizeof(unsigned short));
    if (use_mfma) {
        unsigned short* pool = (unsigned short*)d_ws;
        convw<<<(W_TOT + 255) / 256, 256, 0, stream>>>(
            (const float*)d_in[3], (const float*)d_in[5], (const float*)d_in[7],
            (const float*)d_in[12], (const float*)d_in[14], pool);
        solver<<<GRID, 1024, 0, stream>>>(
            (const float*)d_in[0], pool,
            (const float*)d_in[1], (const float*)d_in[2],
            (const float*)d_in[4], (const float*)d_in[6],
            (const float*)d_in[8], (const float*)d_in[9],
            (const float*)d_in[10], (const float*)d_in[11],
            (const float*)d_in[12], (const float*)d_in[13],
            (const float*)d_in[15], (const int*)d_in[16],
            (float*)d_out);
    } else {
        solver_fb<<<256, NTF, 0, stream>>>(
            (const float*)d_in[0],
            (const float*)d_in[1], (const float*)d_in[2],
            (const float*)d_in[3], (const float*)d_in[4],
            (const float*)d_in[5], (const float*)d_in[6],
            (const float*)d_in[7], (const float*)d_in[8],
            (const float*)d_in[9], (const float*)d_in[10],
            (const float*)d_in[11],
            (const float*)d_in[12], (const float*)d_in[13],
            (const float*)d_in[14], (const float*)d_in[15],
            (const int*)d_in[16],
            (float*)d_out);
    }
}

// Round 6
// 21616.930 us; speedup vs baseline: 25.0644x; 2.0208x over previous
//
#include <hip/hip_runtime.h>
#include <math.h>

#define S_LEN 2048
#define FIN 9
#define NOUT 8
#define LBK 3
#define DD 11
#define K1 33
#define H2 512
#define UU 256
#define NSTEP 2044
#define MR 8
#define GRID 128
#define LN_EPS 1e-3f

typedef __attribute__((ext_vector_type(8))) short short8;
typedef __attribute__((ext_vector_type(4))) float f32x4;
typedef __attribute__((ext_vector_type(4))) unsigned short us4;

// ---- packed B-fragment pool (bf16): tile (nt,kt): 64 lanes x 8 bf16,
// elem = B[k][n], k = kt*32 + (lane>>4)*8 + j, n = nt*16 + (lane&15)
#define F_EW1 (32 * 2 * 512)
#define F_EW2 (16 * 16 * 512)
#define F_UW  (16 * 8 * 512)
#define F_DW1 (32 * 8 * 512)
#define F_DW2 (1 * 16 * 512)
#define O_EW1 0
#define O_EW2 (O_EW1 + F_EW1)
#define O_UW  (O_EW2 + F_EW2)
#define O_DW1 (O_UW + F_UW)
#define O_DW2 (O_DW1 + F_DW1)
#define W_TOT (O_DW2 + F_DW2)   // 368640 elems = 737280 B

__device__ __forceinline__ unsigned short f2bf(float f) {
    unsigned u = __float_as_uint(f);
    u = (u + 0x7fffu + ((u >> 16) & 1u)) >> 16;
    return (unsigned short)u;
}
__device__ __forceinline__ float bf2f(unsigned short u) {
    return __uint_as_float(((unsigned)u) << 16);
}
__device__ __forceinline__ float ftanh(float x) {
    float ax = fabsf(x);
    float e = __expf(-2.0f * ax);
    float r = __fdividef(1.0f - e, 1.0f + e);
    return copysignf(r, x);
}

extern "C" __global__ void convw(const float* __restrict__ ew1, const float* __restrict__ ew2,
                                 const float* __restrict__ uw,  const float* __restrict__ dw1,
                                 const float* __restrict__ dw2, unsigned short* __restrict__ o)
{
    int i = blockIdx.x * blockDim.x + threadIdx.x;
    if (i >= W_TOT) return;
    int p, KT, K, N; const float* W;
    if (i < O_EW2)      { p = i - O_EW1; KT = 2;  K = 33;  N = 512; W = ew1; }
    else if (i < O_UW)  { p = i - O_EW2; KT = 16; K = 512; N = 256; W = ew2; }
    else if (i < O_DW1) { p = i - O_UW;  KT = 8;  K = 256; N = 256; W = uw;  }
    else if (i < O_DW2) { p = i - O_DW1; KT = 8;  K = 256; N = 512; W = dw1; }
    else                { p = i - O_DW2; KT = 16; K = 512; N = 8;   W = dw2; }
    int frag = p >> 9, rem = p & 511;
    int ln = rem >> 3, j = rem & 7;
    int nt = frag / KT, kt = frag % KT;
    int k = kt * 32 + (ln >> 4) * 8 + j;
    int n = nt * 16 + (ln & 15);
    float v = 0.f;
    if (k < K && n < N) v = W[k * N + n];
    o[i] = f2bf(v);
}

extern "C" __global__ void __launch_bounds__(1024, 4)
solver(const float* __restrict__ inputs,
       const unsigned short* __restrict__ pool,
       const float* __restrict__ g1v, const float* __restrict__ b1v,
       const float* __restrict__ eb1, const float* __restrict__ eb2,
       const float* __restrict__ ub,  const float* __restrict__ g2v,
       const float* __restrict__ b2v, const float* __restrict__ bww,
       const float* __restrict__ dw1, const float* __restrict__ db1,
       const float* __restrict__ db2, const int* __restrict__ fixv,
       float* __restrict__ out)
{
    __shared__ unsigned short xs[2][MR * 72];   // LN1 out, double-buffered (33 used, zeros to 64)
    __shared__ unsigned short h1[MR * 520];     // tanh(enc1)
    __shared__ unsigned short hsb[MR * 264];    // enc2 out
    __shared__ __align__(16) float uu[MR * 260];// upd out fp32
    __shared__ unsigned short cmb[MR * 264];    // LN2 out bf16
    __shared__ unsigned short gsb[MR * 520];    // tanh(dec1)
    __shared__ float red2[16][MR][9];           // G partials (16 waves)
    __shared__ float ects[MR];
    __shared__ float s_g1[DD], s_b1[DD];
    __shared__ __align__(16) float s_g2[256], s_b2[256], s_bw[256];

    const int tid = threadIdx.x;
    const int lane = tid & 63;
    const int wv = tid >> 6;      // 0..15
    const int q = lane >> 4;      // 0..3
    const int lc = lane & 15;     // tile col / output col
    const int lr = lc & 7;        // A-row (rows 8..15 duplicate 0..7)
    const int b0 = blockIdx.x * MR;
    const int fx0 = fixv[0], fx1 = fixv[1];

    // ---- preamble ----
    for (int z = tid; z < 2 * MR * 72; z += 1024) (&xs[0][0])[z] = 0;
    for (int z = tid; z < 256; z += 1024) { s_g2[z] = g2v[z]; s_b2[z] = b2v[z]; s_bw[z] = bww[z]; }
    if (tid >= 256 && tid < 256 + DD) { s_g1[tid - 256] = g1v[tid - 256]; s_b1[tid - 256] = b1v[tid - 256]; }

    // ---- pinned step-invariant fragments (baseline budget: 36 regs) ----
    short8 fD[8];
    #pragma unroll
    for (int kt = 0; kt < 8; ++kt)
        fD[kt] = *(const short8*)&pool[O_UW + (((wv << 3) + kt) << 9) + (lane << 3)];
    short8 fG = *(const short8*)&pool[O_DW2 + (wv << 9) + (lane << 3)];

    // per-wave bias/scale scalars
    const float bB0 = eb1[(2 * wv) * 16 + lc];
    const float bB1 = eb1[(2 * wv + 1) * 16 + lc];
    const float bC  = eb2[wv * 16 + lc];
    const float bD  = ub[wv * 16 + lc];
    const float bF0 = db1[(2 * wv) * 16 + lc];
    const float bF1 = db1[(2 * wv + 1) * 16 + lc];
    const float wE0 = dw1[256 * 512 + (2 * wv) * 16 + lc];
    const float wE1 = dw1[256 * 512 + (2 * wv + 1) * 16 + lc];
    const float db2r = db2[lane & 7];

    __syncthreads();

    // ---- stage A for t=0 (window rows straight from inputs) ----
    if (tid < MR * LBK) {
        int r = tid / LBK, p = tid % LBK;
        int b = b0 + r;
        float ld = inputs[((size_t)b * S_LEN + p) * FIN];
        float df = (p > 0) ? ld - inputs[((size_t)b * S_LEN + p - 1) * FIN] : 0.f;
        float v[DD];
        v[0] = ld; v[1] = ld; v[2] = df;
        #pragma unroll
        for (int f = 0; f < NOUT; ++f) v[3 + f] = inputs[((size_t)b * S_LEN + p) * FIN + 1 + f];
        float m = 0.f;
        #pragma unroll
        for (int j = 0; j < DD; ++j) m += v[j];
        m *= (1.0f / DD);
        float var = 0.f;
        #pragma unroll
        for (int j = 0; j < DD; ++j) { float d = v[j] - m; var += d * d; }
        var *= (1.0f / DD);
        float rs = rsqrtf(var + LN_EPS);
        #pragma unroll
        for (int j = 0; j < DD; ++j)
            xs[0][r * 72 + p * DD + j] = f2bf((v[j] - m) * rs * s_g1[j] + s_b1[j]);
    }
    __syncthreads();

    for (int t = 0; t < NSTEP; ++t) {
        unsigned short* xc = &xs[t & 1][0];
        unsigned short* xn = &xs[(t & 1) ^ 1][0];

        // ---- wave 0: prefetch finalize inputs for THIS step; latency hides under B..F ----
        float pLd = 0.f, pPrev = 0.f, pF0 = 0.f, pF1 = 0.f;
        if (wv == 0) {
            const int r8 = lane & 7;
            const int rr = lane >> 3;
            pLd   = inputs[((size_t)(b0 + r8) * S_LEN + t + 3) * FIN];
            pPrev = inputs[((size_t)(b0 + r8) * S_LEN + t + 2) * FIN];
            pF0   = inputs[((size_t)(b0 + rr) * S_LEN + t + 4) * FIN + 1 + fx0];
            pF1   = inputs[((size_t)(b0 + rr) * S_LEN + t + 4) * FIN + 1 + fx1];
        }

        // ==== stage B: h1 = tanh(x @ ew1 + eb1), 33(pad64)->512 ; 16 waves x 2 tiles (streamed) ====
        {
            short8 a0 = *(const short8*)&xc[lr * 72 + q * 8];
            short8 a1 = *(const short8*)&xc[lr * 72 + 32 + q * 8];
            short8 b00 = *(const short8*)&pool[O_EW1 + ((((2 * wv)     << 1) + 0) << 9) + (lane << 3)];
            short8 b01 = *(const short8*)&pool[O_EW1 + ((((2 * wv)     << 1) + 1) << 9) + (lane << 3)];
            short8 b10 = *(const short8*)&pool[O_EW1 + ((((2 * wv + 1) << 1) + 0) << 9) + (lane << 3)];
            short8 b11 = *(const short8*)&pool[O_EW1 + ((((2 * wv + 1) << 1) + 1) << 9) + (lane << 3)];
            f32x4 acc0 = {bB0, bB0, bB0, bB0};
            f32x4 acc1 = {bB1, bB1, bB1, bB1};
            acc0 = __builtin_amdgcn_mfma_f32_16x16x32_bf16(a0, b00, acc0, 0, 0, 0);
            acc0 = __builtin_amdgcn_mfma_f32_16x16x32_bf16(a1, b01, acc0, 0, 0, 0);
            acc1 = __builtin_amdgcn_mfma_f32_16x16x32_bf16(a0, b10, acc1, 0, 0, 0);
            acc1 = __builtin_amdgcn_mfma_f32_16x16x32_bf16(a1, b11, acc1, 0, 0, 0);
            if (q < 2) {
                const int c0 = (2 * wv) * 16 + lc, c1 = (2 * wv + 1) * 16 + lc;
                #pragma unroll
                for (int r = 0; r < 4; ++r) {
                    h1[(q * 4 + r) * 520 + c0] = f2bf(ftanh(acc0[r]));
                    h1[(q * 4 + r) * 520 + c1] = f2bf(ftanh(acc1[r]));
                }
            }
        }
        __syncthreads();

        // ==== stage C: h = h1 @ ew2 + eb2, 512->256 ; 16 waves x 1 tile (streamed B) ====
        {
            f32x4 c0 = {bC, bC, bC, bC};
            f32x4 c1 = {0.f, 0.f, 0.f, 0.f};
            #pragma unroll 4
            for (int k = 0; k < 16; ++k) {
                short8 av = *(const short8*)&h1[lr * 520 + k * 32 + q * 8];
                short8 bf = *(const short8*)&pool[O_EW2 + (((wv << 4) + k) << 9) + (lane << 3)];
                if (k & 1) c1 = __builtin_amdgcn_mfma_f32_16x16x32_bf16(av, bf, c1, 0, 0, 0);
                else       c0 = __builtin_amdgcn_mfma_f32_16x16x32_bf16(av, bf, c0, 0, 0, 0);
            }
            c0 += c1;
            if (q < 2) {
                const int col = wv * 16 + lc;
                #pragma unroll
                for (int r = 0; r < 4; ++r)
                    hsb[(q * 4 + r) * 264 + col] = f2bf(c0[r]);
            }
        }
        __syncthreads();

        // ==== stage D: u = h @ uw + ub ; 16 waves x 1 tile (pinned fD) ====
        {
            f32x4 d0 = {bD, bD, bD, bD};
            f32x4 d1 = {0.f, 0.f, 0.f, 0.f};
            #pragma unroll
            for (int k = 0; k < 8; k += 2) {
                short8 a0 = *(const short8*)&hsb[lr * 264 + k * 32 + q * 8];
                short8 a1 = *(const short8*)&hsb[lr * 264 + (k + 1) * 32 + q * 8];
                d0 = __builtin_amdgcn_mfma_f32_16x16x32_bf16(a0, fD[k],     d0, 0, 0, 0);
                d1 = __builtin_amdgcn_mfma_f32_16x16x32_bf16(a1, fD[k + 1], d1, 0, 0, 0);
            }
            d0 += d1;
            if (q < 2) {
                const int col = wv * 16 + lc;
                #pragma unroll
                for (int r = 0; r < 4; ++r)
                    uu[(q * 4 + r) * 260 + col] = d0[r];
            }
        }
        __syncthreads();

        // ==== LN2 stats + cmb (waves 0..7, row = wv); wave 8 copies xs rows 0,1 for t+1 ====
        if (wv < 8) {
            const int r = wv;
            float4 u4 = *(const float4*)&uu[r * 260 + lane * 4];
            us4 h4 = *(const us4*)&hsb[r * 264 + lane * 4];
            float4 bw4 = *(const float4*)&s_bw[lane * 4];
            float s0 = u4.x + u4.y + u4.z + u4.w;
            float s1 = u4.x * u4.x + u4.y * u4.y + u4.z * u4.z + u4.w * u4.w;
            float s2 = bf2f(h4[0]) * bw4.x + bf2f(h4[1]) * bw4.y + bf2f(h4[2]) * bw4.z + bf2f(h4[3]) * bw4.w;
            #pragma unroll
            for (int mk = 1; mk < 64; mk <<= 1) {
                s0 += __shfl_xor(s0, mk);
                s1 += __shfl_xor(s1, mk);
                s2 += __shfl_xor(s2, mk);
            }
            float mean = s0 * (1.0f / UU);
            float var = s1 * (1.0f / UU) - mean * mean;
            float rstd = rsqrtf(var + LN_EPS);
            if (lane == 0) ects[r] = s2;
            float4 g4 = *(const float4*)&s_g2[lane * 4];
            float4 bb4 = *(const float4*)&s_b2[lane * 4];
            us4 o;
            o[0] = f2bf((u4.x - mean) * rstd * g4.x + bb4.x);
            o[1] = f2bf((u4.y - mean) * rstd * g4.y + bb4.y);
            o[2] = f2bf((u4.z - mean) * rstd * g4.z + bb4.z);
            o[3] = f2bf((u4.w - mean) * rstd * g4.w + bb4.w);
            *(us4*)&cmb[r * 264 + lane * 4] = o;
        } else if (wv == 8) {
            // xs(t+1) rows 0,1 == xs(t) rows 1,2 (identical LN inputs) -> plain copy
            #pragma unroll
            for (int i = 0; i < 3; ++i) {
                int idx = lane + (i << 6);
                if (idx < 176) {
                    int rr = idx / 22;
                    int cc = idx - rr * 22;
                    xn[rr * 72 + cc] = xc[rr * 72 + 11 + cc];
                }
            }
        }
        __syncthreads();

        // ==== stage F: g = tanh(comb @ dw1 + ect*w257 + db1) ; 16 waves x 2 tiles,
        //      A-frags read inline from LDS (R0 form — no register array, no spill).
        //      stage G fused (pinned fG) ====
        {
            float er0 = ects[(q * 4 + 0) & 7];
            float er1 = ects[(q * 4 + 1) & 7];
            float er2 = ects[(q * 4 + 2) & 7];
            float er3 = ects[(q * 4 + 3) & 7];
            #pragma unroll
            for (int tt = 0; tt < 2; ++tt) {
                const float bias = (tt == 0) ? bF0 : bF1;
                const float wc   = (tt == 0) ? wE0 : wE1;
                f32x4 ac0 = {bias, bias, bias, bias};
                f32x4 ac1 = {0.f, 0.f, 0.f, 0.f};
                #pragma unroll 4
                for (int k = 0; k < 8; ++k) {
                    short8 af = *(const short8*)&cmb[lr * 264 + k * 32 + q * 8];
                    short8 bf = *(const short8*)&pool[O_DW1 + ((((2 * wv + tt) << 3) + k) << 9) + (lane << 3)];
                    if (k & 1) ac1 = __builtin_amdgcn_mfma_f32_16x16x32_bf16(af, bf, ac1, 0, 0, 0);
                    else       ac0 = __builtin_amdgcn_mfma_f32_16x16x32_bf16(af, bf, ac0, 0, 0, 0);
                }
                ac0 += ac1;
                if (q < 2) {
                    const int col = (2 * wv + tt) * 16 + lc;
                    gsb[(q * 4 + 0) * 520 + col] = f2bf(ftanh(ac0[0] + er0 * wc));
                    gsb[(q * 4 + 1) * 520 + col] = f2bf(ftanh(ac0[1] + er1 * wc));
                    gsb[(q * 4 + 2) * 520 + col] = f2bf(ftanh(ac0[2] + er2 * wc));
                    gsb[(q * 4 + 3) * 520 + col] = f2bf(ftanh(ac0[3] + er3 * wc));
                }
            }
            // G: wave wv owns kt=wv; gsb cols [32wv,32wv+32) were written by this wave
            f32x4 ag = {0.f, 0.f, 0.f, 0.f};
            short8 ga = *(const short8*)&gsb[lr * 520 + wv * 32 + q * 8];
            ag = __builtin_amdgcn_mfma_f32_16x16x32_bf16(ga, fG, ag, 0, 0, 0);
            if (q < 2 && lc < 8) {
                #pragma unroll
                for (int r = 0; r < 4; ++r)
                    red2[wv][q * 4 + r][lc] = ag[r];
            }
        }
        __syncthreads();

        // ==== finalize (wave 0): y, out, xs(t+1) row 2 (prefetched inputs, shfl-gathered y) ====
        if (wv == 0) {
            const int r = lane >> 3, f = lane & 7;
            const int b = b0 + r;
            float a0  = red2[0][r][f],  a1  = red2[1][r][f],  a2  = red2[2][r][f],  a3  = red2[3][r][f];
            float a4  = red2[4][r][f],  a5  = red2[5][r][f],  a6  = red2[6][r][f],  a7  = red2[7][r][f];
            float a8  = red2[8][r][f],  a9  = red2[9][r][f],  a10 = red2[10][r][f], a11 = red2[11][r][f];
            float a12 = red2[12][r][f], a13 = red2[13][r][f], a14 = red2[14][r][f], a15 = red2[15][r][f];
            float y = db2r + ((((a0 + a1) + (a2 + a3)) + ((a4 + a5) + (a6 + a7)))
                            + (((a8 + a9) + (a10 + a11)) + ((a12 + a13) + (a14 + a15))));
            if (f == fx0) y = pF0;
            if (f == fx1) y = pF1;
            out[((size_t)(f * 1024 + b)) * NSTEP + t] = y;
            // gather this step's y row for the row-2 LN (lane rr<8 uses lanes rr*8..rr*8+7)
            float w8[8];
            #pragma unroll
            for (int ff = 0; ff < 8; ++ff) w8[ff] = __shfl(y, ((lane & 7) << 3) + ff);
            if (lane < 8) {
                float v[DD];
                v[0] = pLd; v[1] = pLd; v[2] = pLd - pPrev;
                #pragma unroll
                for (int ff = 0; ff < NOUT; ++ff) v[3 + ff] = w8[ff];
                float m = 0.f;
                #pragma unroll
                for (int j = 0; j < DD; ++j) m += v[j];
                m *= (1.0f / DD);
                float var = 0.f;
                #pragma unroll
                for (int j = 0; j < DD; ++j) { float d = v[j] - m; var += d * d; }
                var *= (1.0f / DD);
                float rs = rsqrtf(var + LN_EPS);
                #pragma unroll
                for (int j = 0; j < DD; ++j)
                    xn[lane * 72 + 22 + j] = f2bf((v[j] - m) * rs * s_g1[j] + s_b1[j]);
            }
        }
        __syncthreads();
    }
}

// ================= fallback (fp32 VALU, R3-proven) =================
#define MROW 4
#define NTF 1024
__global__ __launch_bounds__(NTF)
void solver_fb(const float* __restrict__ inputs,
               const float* __restrict__ g1v, const float* __restrict__ b1v,
               const float* __restrict__ ew1, const float* __restrict__ eb1,
               const float* __restrict__ ew2, const float* __restrict__ eb2,
               const float* __restrict__ uw,  const float* __restrict__ ub,
               const float* __restrict__ g2v, const float* __restrict__ b2v,
               const float* __restrict__ bww,
               const float* __restrict__ dw1, const float* __restrict__ db1,
               const float* __restrict__ dw2, const float* __restrict__ db2,
               const int* __restrict__ fixv,
               float* __restrict__ out)
{
    __shared__ float x33[MROW][K1];
    __shared__ float h1s[MROW * H2];
    __shared__ float hs[MROW * UU];
    __shared__ float combs[MROW][UU + 1];
    __shared__ float gs[MROW * H2];
    __shared__ float win[MROW][LBK][NOUT];
    __shared__ float redf[8192];
    __shared__ float red2[32][32];
    __shared__ float wred[16][3];
    __shared__ float rowstat[MROW][3];
    __shared__ float ynew[MROW][NOUT];
    float2* redf2 = reinterpret_cast<float2*>(redf);
    const int tid = threadIdx.x;
    const int b0 = blockIdx.x * MROW;
    const int fx0 = fixv[0], fx1 = fixv[1];
    if (tid < MROW * LBK * NOUT) {
        int r = tid / (LBK * NOUT);
        int rem = tid % (LBK * NOUT);
        int p = rem / NOUT, f = rem % NOUT;
        win[r][p][f] = inputs[((size_t)(b0 + r) * S_LEN + p) * FIN + 1 + f];
    }
    __syncthreads();
    for (int t = 0; t < NSTEP; ++t) {
        const int i = t + LBK;
        if (tid < MROW * LBK) {
            int r = tid / LBK, p = tid % LBK;
            int b = b0 + r;
            int tt = i - LBK + p;
            float ld = inputs[((size_t)b * S_LEN + tt) * FIN];
            float df = (tt > 0) ? ld - inputs[((size_t)b * S_LEN + tt - 1) * FIN] : 0.f;
            float v[DD];
            v[0] = ld; v[1] = ld; v[2] = df;
            #pragma unroll
            for (int f = 0; f < NOUT; ++f) v[3 + f] = win[r][p][f];
            float m = 0.f;
            #pragma unroll
            for (int j = 0; j < DD; ++j) m += v[j];
            m *= (1.0f / DD);
            float var = 0.f;
            #pragma unroll
            for (int j = 0; j < DD; ++j) { float d = v[j] - m; var += d * d; }
            var *= (1.0f / DD);
            float rs = rsqrtf(var + LN_EPS);
            #pragma unroll
            for (int j = 0; j < DD; ++j)
                x33[r][p * DD + j] = (v[j] - m) * rs * g1v[j] + b1v[j];
        }
        __syncthreads();
        {
            int cc = tid & 255, c0 = cc * 2;
            int ks = tid >> 8;
            int kbeg = ks * 8;
            int kend = (ks == 3) ? K1 : kbeg + 8;
            float2 acc[MROW];
            #pragma unroll
            for (int r = 0; r < MROW; ++r) acc[r] = make_float2(0.f, 0.f);
            for (int k = kbeg; k < kend; ++k) {
                float2 w = *reinterpret_cast<const float2*>(ew1 + (size_t)k * H2 + c0);
                #pragma unroll
                for (int r = 0; r < MROW; ++r) {
                    float xv = x33[r][k];
                    acc[r].x += xv * w.x; acc[r].y += xv * w.y;
                }
            }
            #pragma unroll
            for (int r = 0; r < MROW; ++r) redf2[ks * 1024 + r * 256 + cc] = acc[r];
        }
        __syncthreads();
        {
            #pragma unroll
            for (int jj = 0; jj < 2; ++jj) {
                int o = tid + jj * 1024;
                float v = redf[o] + redf[2048 + o] + redf[4096 + o] + redf[6144 + o] + eb1[o & 511];
                h1s[o] = tanhf(v);
            }
        }
        __syncthreads();
        {
            int cc = tid & 127, c0 = cc * 2;
            int ks = tid >> 7;
            int kbeg = ks * 64;
            float2 acc[MROW];
            #pragma unroll
            for (int r = 0; r < MROW; ++r) acc[r] = make_float2(0.f, 0.f);
            #pragma unroll 8
            for (int k = kbeg; k < kbeg + 64; ++k) {
                float2 w = *reinterpret_cast<const float2*>(ew2 + (size_t)k * UU + c0);
                #pragma unroll
                for (int r = 0; r < MROW; ++r) {
                    float hv = h1s[r * H2 + k];
                    acc[r].x += hv * w.x; acc[r].y += hv * w.y;
                }
            }
            #pragma unroll
            for (int r = 0; r < MROW; ++r) redf2[ks * 512 + r * 128 + cc] = acc[r];
        }
        __syncthreads();
        {
            int o = tid;
            float v = eb2[o & 255];
            #pragma unroll
            for (int ks = 0; ks < 8; ++ks) v += redf[ks * 1024 + o];
            hs[o] = v;
        }
        __syncthreads();
        {
            int cc = tid & 127, c0 = cc * 2;
            int ks = tid >> 7;
            int kbeg = ks * 32;
            float2 acc[MROW];
            #pragma unroll
            for (int r = 0; r < MROW; ++r) acc[r] = make_float2(0.f, 0.f);
            #pragma unroll 8
            for (int k = kbeg; k < kbeg + 32; ++k) {
                float2 w = *reinterpret_cast<const float2*>(uw + (size_t)k * UU + c0);
                #pragma unroll
                for (int r = 0; r < MROW; ++r) {
                    float hv = hs[r * UU + k];
                    acc[r].x += hv * w.x; acc[r].y += hv * w.y;
                }
            }
            #pragma unroll
            for (int r = 0; r < MROW; ++r) redf2[ks * 512 + r * 128 + cc] = acc[r];
        }
        __syncthreads();
        {
            int o = tid, r = o >> 8, c = o & 255;
            float v = ub[c];
            #pragma unroll
            for (int ks = 0; ks < 8; ++ks) v += redf[ks * 1024 + o];
            combs[r][c] = v;
        }
        __syncthreads();
        {
            int r = tid >> 8, c = tid & 255;
            float u = combs[r][c];
            float hb = hs[r * UU + c] * bww[c];
            float s0 = u, s1 = u * u, s2 = hb;
            #pragma unroll
            for (int mk = 1; mk < 64; mk <<= 1) {
                s0 += __shfl_xor(s0, mk);
                s1 += __shfl_xor(s1, mk);
                s2 += __shfl_xor(s2, mk);
            }
            if ((tid & 63) == 0) {
                int w = tid >> 6;
                wred[w][0] = s0; wred[w][1] = s1; wred[w][2] = s2;
            }
        }
        __syncthreads();
        if (tid < MROW) {
            int r = tid;
            float t0 = 0.f, t1 = 0.f, t2 = 0.f;
            #pragma unroll
            for (int w = 4 * r; w < 4 * r + 4; ++w) { t0 += wred[w][0]; t1 += wred[w][1]; t2 += wred[w][2]; }
            float mean = t0 * (1.0f / UU);
            float var = t1 * (1.0f / UU) - mean * mean;
            rowstat[r][0] = mean; rowstat[r][1] = rsqrtf(var + LN_EPS); rowstat[r][2] = t2;
        }
        __syncthreads();
        {
            int r = tid >> 8, c = tid & 255;
            float u = combs[r][c];
            combs[r][c] = (u - rowstat[r][0]) * rowstat[r][1] * g2v[c] + b2v[c];
            if (tid < MROW) combs[tid][UU] = rowstat[tid][2];
        }
        __syncthreads();
        {
            int cc = tid & 255, c0 = cc * 2;
            int ks = tid >> 8;
            int kbeg = ks * 64;
            int kend = (ks == 3) ? (UU + 1) : kbeg + 64;
            float2 acc[MROW];
            #pragma unroll
            for (int r = 0; r < MROW; ++r) acc[r] = make_float2(0.f, 0.f);
            #pragma unroll 8
            for (int k = kbeg; k < kend; ++k) {
                float2 w = *reinterpret_cast<const float2*>(dw1 + (size_t)k * H2 + c0);
                #pragma unroll
                for (int r = 0; r < MROW; ++r) {
                    float cv = combs[r][k];
                    acc[r].x += cv * w.x; acc[r].y += cv * w.y;
                }
            }
            #pragma unroll
            for (int r = 0; r < MROW; ++r) redf2[ks * 1024 + r * 256 + cc] = acc[r];
        }
        __syncthreads();
        {
            #pragma unroll
            for (int jj = 0; jj < 2; ++jj) {
                int o = tid + jj * 1024;
                float v = redf[o] + redf[2048 + o] + redf[4096 + o] + redf[6144 + o] + db1[o & 511];
                gs[o] = tanhf(v);
            }
        }
        __syncthreads();
        {
            int o = tid & 31, kc = tid >> 5;
            int r = o >> 3, f = o & 7;
            int kbeg = kc * 16;
            float p = 0.f;
            #pragma unroll 4
            for (int k = kbeg; k < kbeg + 16; ++k)
                p += gs[r * H2 + k] * dw2[(size_t)k * NOUT + f];
            red2[kc][o] = p;
        }
        __syncthreads();
        if (tid < 32) {
            int o = tid, r = o >> 3, f = o & 7;
            int b = b0 + r;
            float y = db2[f];
            #pragma unroll
            for (int kc = 0; kc < 32; ++kc) y += red2[kc][o];
            if (f == fx0) y = inputs[((size_t)b * S_LEN + i + 1) * FIN + 1 + fx0];
            if (f == fx1) y = inputs[((size_t)b * S_LEN + i + 1) * FIN + 1 + fx1];
            ynew[r][f] = y;
            out[((size_t)(f * 1024 + b)) * NSTEP + t] = y;
        }
        __syncthreads();
        {
            float wshift = 0.f;
            int sr = 0, sp = 0, sf = 0;
            bool doshift = tid < MROW * LBK * NOUT;
            if (doshift) {
                sr = tid / (LBK * NOUT);
                int rem = tid % (LBK * NOUT);
                sp = rem / NOUT; sf = rem % NOUT;
                wshift = (sp < LBK - 1) ? win[sr][sp + 1][sf] : ynew[sr][sf];
            }
            __syncthreads();
            if (doshift) win[sr][sp][sf] = wshift;
        }
        __syncthreads();
    }
}

extern "C" void kernel_launch(void* const* d_in, const int* in_sizes, int n_in,
                              void* d_out, int out_size, void* d_ws, size_t ws_size,
                              hipStream_t stream) {
    (void)in_sizes; (void)n_in; (void)out_size;
    const bool use_mfma = (d_ws != nullptr) && (ws_size >= (size_t)W_TOT * sizeof(unsigned short));
    if (use_mfma) {
        unsigned short* pool = (unsigned short*)d_ws;
        convw<<<(W_TOT + 255) / 256, 256, 0, stream>>>(
            (const float*)d_in[3], (const float*)d_in[5], (const float*)d_in[7],
            (const float*)d_in[12], (const float*)d_in[14], pool);
        solver<<<GRID, 1024, 0, stream>>>(
            (const float*)d_in[0], pool,
            (const float*)d_in[1], (const float*)d_in[2],
            (const float*)d_in[4], (const float*)d_in[6],
            (const float*)d_in[8], (const float*)d_in[9],
            (const float*)d_in[10], (const float*)d_in[11],
            (const float*)d_in[12], (const float*)d_in[13],
            (const float*)d_in[15], (const int*)d_in[16],
            (float*)d_out);
    } else {
        solver_fb<<<256, NTF, 0, stream>>>(
            (const float*)d_in[0],
            (const float*)d_in[1], (const float*)d_in[2],
            (const float*)d_in[3], (const float*)d_in[4],
            (const float*)d_in[5], (const float*)d_in[6],
            (const float*)d_in[7], (const float*)d_in[8],
            (const float*)d_in[9], (const float*)d_in[10],
            (const float*)d_in[11],
            (const float*)d_in[12], (const float*)d_in[13],
            (const float*)d_in[14], (const float*)d_in[15],
            (const int*)d_in[16],
            (float*)d_out);
    }
}

// Round 7
// 15359.322 us; speedup vs baseline: 35.2760x; 1.4074x over previous
//
#include <hip/hip_runtime.h>
#include <math.h>

#define S_LEN 2048
#define FIN 9
#define NOUT 8
#define LBK 3
#define DD 11
#define K1 33
#define H2 512
#define UU 256
#define NSTEP 2044
#define MR 8
#define GRID 128
#define LN_EPS 1e-3f

typedef __attribute__((ext_vector_type(8))) short short8;
typedef __attribute__((ext_vector_type(4))) float f32x4;
typedef __attribute__((ext_vector_type(4))) unsigned short us4;

// ---- packed B-fragment pool (bf16): tile (nt,kt): 64 lanes x 8 bf16,
// elem = B[k][n], k = kt*32 + (lane>>4)*8 + j, n = nt*16 + (lane&15)
// O_EW2 region now holds W2U = ew2 @ uw (512->256) fragments.
// O_UW region head holds fp32 aux: [0..255]=bU' (eb2@uw+ub), [256..767]=w2b (ew2@bww), [768]=c0b (eb2@bww)
#define F_EW1 (32 * 2 * 512)
#define F_EW2 (16 * 16 * 512)
#define F_UW  (16 * 8 * 512)
#define F_DW1 (32 * 8 * 512)
#define F_DW2 (1 * 16 * 512)
#define O_EW1 0
#define O_EW2 (O_EW1 + F_EW1)
#define O_UW  (O_EW2 + F_EW2)
#define O_DW1 (O_UW + F_UW)
#define O_DW2 (O_DW1 + F_DW1)
#define W_TOT (O_DW2 + F_DW2)   // 368640 elems = 737280 B

__device__ __forceinline__ unsigned short f2bf(float f) {
    unsigned u = __float_as_uint(f);
    u = (u + 0x7fffu + ((u >> 16) & 1u)) >> 16;
    return (unsigned short)u;
}
__device__ __forceinline__ float bf2f(unsigned short u) {
    return __uint_as_float(((unsigned)u) << 16);
}
__device__ __forceinline__ float ftanh(float x) {
    float ax = fabsf(x);
    float e = __expf(-2.0f * ax);
    float r = __fdividef(1.0f - e, 1.0f + e);
    return copysignf(r, x);
}

extern "C" __global__ void convw(const float* __restrict__ ew1, const float* __restrict__ ew2,
                                 const float* __restrict__ uw,  const float* __restrict__ dw1,
                                 const float* __restrict__ dw2, unsigned short* __restrict__ o)
{
    int i = blockIdx.x * blockDim.x + threadIdx.x;
    if (i >= W_TOT) return;
    int p, KT, K, N; const float* W;
    bool fuse = false;
    if (i < O_EW2)      { p = i - O_EW1; KT = 2;  K = 33;  N = 512; W = ew1; }
    else if (i < O_UW)  { p = i - O_EW2; KT = 16; K = 512; N = 256; W = ew2; fuse = true; }
    else if (i < O_DW1) { p = i - O_UW;  KT = 8;  K = 256; N = 256; W = uw;  }
    else if (i < O_DW2) { p = i - O_DW1; KT = 8;  K = 256; N = 512; W = dw1; }
    else                { p = i - O_DW2; KT = 16; K = 512; N = 8;   W = dw2; }
    int frag = p >> 9, rem = p & 511;
    int ln = rem >> 3, j = rem & 7;
    int nt = frag / KT, kt = frag % KT;
    int k = kt * 32 + (ln >> 4) * 8 + j;
    int n = nt * 16 + (ln & 15);
    float v = 0.f;
    if (k < K && n < N) {
        if (fuse) {
            // W2U[k][n] = sum_j ew2[k][j] * uw[j][n]
            const float* e2 = ew2 + (size_t)k * UU;
            float acc = 0.f;
            #pragma unroll 4
            for (int jj = 0; jj < UU; ++jj) acc += e2[jj] * uw[(size_t)jj * UU + n];
            v = acc;
        } else {
            v = W[k * N + n];
        }
    }
    o[i] = f2bf(v);
}

// aux: bU'[n] = eb2@uw + ub ; w2b[k] = ew2@bww ; c0b = eb2@bww  (fp32, into pool+O_UW)
extern "C" __global__ void convaux(const float* __restrict__ ew2, const float* __restrict__ eb2,
                                   const float* __restrict__ uw,  const float* __restrict__ ub,
                                   const float* __restrict__ bww, float* __restrict__ auxf)
{
    int tid = blockIdx.x * blockDim.x + threadIdx.x;
    if (tid < 256) {
        float v = ub[tid];
        for (int j = 0; j < UU; ++j) v += eb2[j] * uw[(size_t)j * UU + tid];
        auxf[tid] = v;
    } else if (tid < 768) {
        int k = tid - 256;
        float v = 0.f;
        for (int j = 0; j < UU; ++j) v += ew2[(size_t)k * UU + j] * bww[j];
        auxf[256 + k] = v;
    } else if (tid == 768) {
        float v = 0.f;
        for (int j = 0; j < UU; ++j) v += eb2[j] * bww[j];
        auxf[768] = v;
    }
}

extern "C" __global__ void __launch_bounds__(1024, 4)
solver(const float* __restrict__ inputs,
       const unsigned short* __restrict__ pool,
       const float* __restrict__ g1v, const float* __restrict__ b1v,
       const float* __restrict__ eb1, const float* __restrict__ eb2,
       const float* __restrict__ ub,  const float* __restrict__ g2v,
       const float* __restrict__ b2v, const float* __restrict__ bww,
       const float* __restrict__ dw1, const float* __restrict__ db1,
       const float* __restrict__ db2, const int* __restrict__ fixv,
       float* __restrict__ out)
{
    __shared__ unsigned short xs[2][MR * 72];   // LN1 out, double-buffered (33 used, zeros to 64)
    __shared__ unsigned short h1[MR * 520];     // tanh(enc1)
    __shared__ __align__(16) float uu[MR * 260];// fused enc2+upd out fp32
    __shared__ unsigned short cmb[MR * 264];    // LN2 out bf16
    __shared__ unsigned short gsb[MR * 520];    // tanh(dec1)
    __shared__ float red2[16][MR][9];           // G partials (16 waves)
    __shared__ float ects[MR];
    __shared__ float s_g1[DD], s_b1[DD];
    __shared__ __align__(16) float s_g2[256], s_b2[256];
    __shared__ __align__(16) float s_w2b[512];  // ew2 @ beta_w

    const int tid = threadIdx.x;
    const int lane = tid & 63;
    const int wv = tid >> 6;      // 0..15
    const int q = lane >> 4;      // 0..3
    const int lc = lane & 15;     // tile col / output col
    const int lr = lc & 7;        // A-row (rows 8..15 duplicate 0..7)
    const int b0 = blockIdx.x * MR;
    const int fx0 = fixv[0], fx1 = fixv[1];
    const float* auxf = (const float*)(pool + O_UW);

    // ---- preamble ----
    for (int z = tid; z < 2 * MR * 72; z += 1024) (&xs[0][0])[z] = 0;
    for (int z = tid; z < 256; z += 1024) { s_g2[z] = g2v[z]; s_b2[z] = b2v[z]; }
    for (int z = tid; z < 512; z += 1024) s_w2b[z] = auxf[256 + z];
    if (tid >= 512 && tid < 512 + DD) { s_g1[tid - 512] = g1v[tid - 512]; s_b1[tid - 512] = b1v[tid - 512]; }

    // ---- pinned step-invariant fragments: only fG (4 VGPR) ----
    short8 fG = *(const short8*)&pool[O_DW2 + (wv << 9) + (lane << 3)];

    // per-wave bias/scale scalars
    const float bB0 = eb1[(2 * wv) * 16 + lc];
    const float bB1 = eb1[(2 * wv + 1) * 16 + lc];
    const float bCD = auxf[wv * 16 + lc];       // fused eb2@uw + ub
    const float c0b = auxf[768];                // eb2@bww
    const float bF0 = db1[(2 * wv) * 16 + lc];
    const float bF1 = db1[(2 * wv + 1) * 16 + lc];
    const float wE0 = dw1[256 * 512 + (2 * wv) * 16 + lc];
    const float wE1 = dw1[256 * 512 + (2 * wv + 1) * 16 + lc];
    const float db2r = db2[lane & 7];

    __syncthreads();

    // ---- stage A for t=0 (window rows straight from inputs) ----
    if (tid < MR * LBK) {
        int r = tid / LBK, p = tid % LBK;
        int b = b0 + r;
        float ld = inputs[((size_t)b * S_LEN + p) * FIN];
        float df = (p > 0) ? ld - inputs[((size_t)b * S_LEN + p - 1) * FIN] : 0.f;
        float v[DD];
        v[0] = ld; v[1] = ld; v[2] = df;
        #pragma unroll
        for (int f = 0; f < NOUT; ++f) v[3 + f] = inputs[((size_t)b * S_LEN + p) * FIN + 1 + f];
        float m = 0.f;
        #pragma unroll
        for (int j = 0; j < DD; ++j) m += v[j];
        m *= (1.0f / DD);
        float var = 0.f;
        #pragma unroll
        for (int j = 0; j < DD; ++j) { float d = v[j] - m; var += d * d; }
        var *= (1.0f / DD);
        float rs = rsqrtf(var + LN_EPS);
        #pragma unroll
        for (int j = 0; j < DD; ++j)
            xs[0][r * 72 + p * DD + j] = f2bf((v[j] - m) * rs * s_g1[j] + s_b1[j]);
    }
    __syncthreads();

    for (int t = 0; t < NSTEP; ++t) {
        unsigned short* xc = &xs[t & 1][0];
        unsigned short* xn = &xs[(t & 1) ^ 1][0];

        // ---- wave 0: prefetch finalize inputs for THIS step; latency hides under B..F ----
        float pLd = 0.f, pPrev = 0.f, pF0 = 0.f, pF1 = 0.f;
        if (wv == 0) {
            const int r8 = lane & 7;
            const int rr = lane >> 3;
            pLd   = inputs[((size_t)(b0 + r8) * S_LEN + t + 3) * FIN];
            pPrev = inputs[((size_t)(b0 + r8) * S_LEN + t + 2) * FIN];
            pF0   = inputs[((size_t)(b0 + rr) * S_LEN + t + 4) * FIN + 1 + fx0];
            pF1   = inputs[((size_t)(b0 + rr) * S_LEN + t + 4) * FIN + 1 + fx1];
        }

        // ==== stage B: h1 = tanh(x @ ew1 + eb1), 33(pad64)->512 ; 16 waves x 2 tiles (streamed) ====
        {
            short8 a0 = *(const short8*)&xc[lr * 72 + q * 8];
            short8 a1 = *(const short8*)&xc[lr * 72 + 32 + q * 8];
            short8 b00 = *(const short8*)&pool[O_EW1 + ((((2 * wv)     << 1) + 0) << 9) + (lane << 3)];
            short8 b01 = *(const short8*)&pool[O_EW1 + ((((2 * wv)     << 1) + 1) << 9) + (lane << 3)];
            short8 b10 = *(const short8*)&pool[O_EW1 + ((((2 * wv + 1) << 1) + 0) << 9) + (lane << 3)];
            short8 b11 = *(const short8*)&pool[O_EW1 + ((((2 * wv + 1) << 1) + 1) << 9) + (lane << 3)];
            f32x4 acc0 = {bB0, bB0, bB0, bB0};
            f32x4 acc1 = {bB1, bB1, bB1, bB1};
            acc0 = __builtin_amdgcn_mfma_f32_16x16x32_bf16(a0, b00, acc0, 0, 0, 0);
            acc0 = __builtin_amdgcn_mfma_f32_16x16x32_bf16(a1, b01, acc0, 0, 0, 0);
            acc1 = __builtin_amdgcn_mfma_f32_16x16x32_bf16(a0, b10, acc1, 0, 0, 0);
            acc1 = __builtin_amdgcn_mfma_f32_16x16x32_bf16(a1, b11, acc1, 0, 0, 0);
            if (q < 2) {
                const int c0 = (2 * wv) * 16 + lc, c1 = (2 * wv + 1) * 16 + lc;
                #pragma unroll
                for (int r = 0; r < 4; ++r) {
                    h1[(q * 4 + r) * 520 + c0] = f2bf(ftanh(acc0[r]));
                    h1[(q * 4 + r) * 520 + c1] = f2bf(ftanh(acc1[r]));
                }
            }
        }
        __syncthreads();

        // ==== stage CD (fused enc2+upd): u = h1 @ W2U + bU' ; 16 waves x 1 tile (streamed) ====
        {
            f32x4 c0 = {bCD, bCD, bCD, bCD};
            f32x4 c1 = {0.f, 0.f, 0.f, 0.f};
            #pragma unroll 4
            for (int k = 0; k < 16; ++k) {
                short8 av = *(const short8*)&h1[lr * 520 + k * 32 + q * 8];
                short8 bf = *(const short8*)&pool[O_EW2 + (((wv << 4) + k) << 9) + (lane << 3)];
                if (k & 1) c1 = __builtin_amdgcn_mfma_f32_16x16x32_bf16(av, bf, c1, 0, 0, 0);
                else       c0 = __builtin_amdgcn_mfma_f32_16x16x32_bf16(av, bf, c0, 0, 0, 0);
            }
            c0 += c1;
            if (q < 2) {
                const int col = wv * 16 + lc;
                #pragma unroll
                for (int r = 0; r < 4; ++r)
                    uu[(q * 4 + r) * 260 + col] = c0[r];
            }
        }
        __syncthreads();

        // ==== LN2 stats + cmb (waves 0..7, row = wv); ect from h1 @ w2b + c0b.
        //      wave 8 copies xs rows 0,1 for t+1 ====
        if (wv < 8) {
            const int r = wv;
            float4 u4 = *(const float4*)&uu[r * 260 + lane * 4];
            const int hb8 = r * 520 + lane * 8;
            us4 ha = *(const us4*)&h1[hb8];
            us4 hb = *(const us4*)&h1[hb8 + 4];
            float4 wA = *(const float4*)&s_w2b[lane * 8];
            float4 wB = *(const float4*)&s_w2b[lane * 8 + 4];
            float s0 = u4.x + u4.y + u4.z + u4.w;
            float s1 = u4.x * u4.x + u4.y * u4.y + u4.z * u4.z + u4.w * u4.w;
            float s2 = bf2f(ha[0]) * wA.x + bf2f(ha[1]) * wA.y + bf2f(ha[2]) * wA.z + bf2f(ha[3]) * wA.w
                     + bf2f(hb[0]) * wB.x + bf2f(hb[1]) * wB.y + bf2f(hb[2]) * wB.z + bf2f(hb[3]) * wB.w;
            #pragma unroll
            for (int mk = 1; mk < 64; mk <<= 1) {
                s0 += __shfl_xor(s0, mk);
                s1 += __shfl_xor(s1, mk);
                s2 += __shfl_xor(s2, mk);
            }
            float mean = s0 * (1.0f / UU);
            float var = s1 * (1.0f / UU) - mean * mean;
            float rstd = rsqrtf(var + LN_EPS);
            if (lane == 0) ects[r] = s2 + c0b;
            float4 g4 = *(const float4*)&s_g2[lane * 4];
            float4 bb4 = *(const float4*)&s_b2[lane * 4];
            us4 o;
            o[0] = f2bf((u4.x - mean) * rstd * g4.x + bb4.x);
            o[1] = f2bf((u4.y - mean) * rstd * g4.y + bb4.y);
            o[2] = f2bf((u4.z - mean) * rstd * g4.z + bb4.z);
            o[3] = f2bf((u4.w - mean) * rstd * g4.w + bb4.w);
            *(us4*)&cmb[r * 264 + lane * 4] = o;
        } else if (wv == 8) {
            // xs(t+1) rows 0,1 == xs(t) rows 1,2 (identical LN inputs) -> plain copy
            #pragma unroll
            for (int i = 0; i < 3; ++i) {
                int idx = lane + (i << 6);
                if (idx < 176) {
                    int rr = idx / 22;
                    int cc = idx - rr * 22;
                    xn[rr * 72 + cc] = xc[rr * 72 + 11 + cc];
                }
            }
        }
        __syncthreads();

        // ==== stage F: g = tanh(comb @ dw1 + ect*w257 + db1) ; 16 waves x 2 tiles,
        //      A-frags read inline from LDS (no register array). stage G fused (pinned fG) ====
        {
            float er0 = ects[(q * 4 + 0) & 7];
            float er1 = ects[(q * 4 + 1) & 7];
            float er2 = ects[(q * 4 + 2) & 7];
            float er3 = ects[(q * 4 + 3) & 7];
            #pragma unroll
            for (int tt = 0; tt < 2; ++tt) {
                const float bias = (tt == 0) ? bF0 : bF1;
                const float wc   = (tt == 0) ? wE0 : wE1;
                f32x4 ac0 = {bias, bias, bias, bias};
                f32x4 ac1 = {0.f, 0.f, 0.f, 0.f};
                #pragma unroll 4
                for (int k = 0; k < 8; ++k) {
                    short8 af = *(const short8*)&cmb[lr * 264 + k * 32 + q * 8];
                    short8 bf = *(const short8*)&pool[O_DW1 + ((((2 * wv + tt) << 3) + k) << 9) + (lane << 3)];
                    if (k & 1) ac1 = __builtin_amdgcn_mfma_f32_16x16x32_bf16(af, bf, ac1, 0, 0, 0);
                    else       ac0 = __builtin_amdgcn_mfma_f32_16x16x32_bf16(af, bf, ac0, 0, 0, 0);
                }
                ac0 += ac1;
                if (q < 2) {
                    const int col = (2 * wv + tt) * 16 + lc;
                    gsb[(q * 4 + 0) * 520 + col] = f2bf(ftanh(ac0[0] + er0 * wc));
                    gsb[(q * 4 + 1) * 520 + col] = f2bf(ftanh(ac0[1] + er1 * wc));
                    gsb[(q * 4 + 2) * 520 + col] = f2bf(ftanh(ac0[2] + er2 * wc));
                    gsb[(q * 4 + 3) * 520 + col] = f2bf(ftanh(ac0[3] + er3 * wc));
                }
            }
            // G: wave wv owns kt=wv; gsb cols [32wv,32wv+32) were written by this wave
            f32x4 ag = {0.f, 0.f, 0.f, 0.f};
            short8 ga = *(const short8*)&gsb[lr * 520 + wv * 32 + q * 8];
            ag = __builtin_amdgcn_mfma_f32_16x16x32_bf16(ga, fG, ag, 0, 0, 0);
            if (q < 2 && lc < 8) {
                #pragma unroll
                for (int r = 0; r < 4; ++r)
                    red2[wv][q * 4 + r][lc] = ag[r];
            }
        }
        __syncthreads();

        // ==== finalize (wave 0): y, out, xs(t+1) row 2 (prefetched inputs, shfl-gathered y) ====
        if (wv == 0) {
            const int r = lane >> 3, f = lane & 7;
            const int b = b0 + r;
            float a0  = red2[0][r][f],  a1  = red2[1][r][f],  a2  = red2[2][r][f],  a3  = red2[3][r][f];
            float a4  = red2[4][r][f],  a5  = red2[5][r][f],  a6  = red2[6][r][f],  a7  = red2[7][r][f];
            float a8  = red2[8][r][f],  a9  = red2[9][r][f],  a10 = red2[10][r][f], a11 = red2[11][r][f];
            float a12 = red2[12][r][f], a13 = red2[13][r][f], a14 = red2[14][r][f], a15 = red2[15][r][f];
            float y = db2r + ((((a0 + a1) + (a2 + a3)) + ((a4 + a5) + (a6 + a7)))
                            + (((a8 + a9) + (a10 + a11)) + ((a12 + a13) + (a14 + a15))));
            if (f == fx0) y = pF0;
            if (f == fx1) y = pF1;
            out[((size_t)(f * 1024 + b)) * NSTEP + t] = y;
            // gather this step's y row for the row-2 LN (lane rr<8 uses lanes rr*8..rr*8+7)
            float w8[8];
            #pragma unroll
            for (int ff = 0; ff < 8; ++ff) w8[ff] = __shfl(y, ((lane & 7) << 3) + ff);
            if (lane < 8) {
                float v[DD];
                v[0] = pLd; v[1] = pLd; v[2] = pLd - pPrev;
                #pragma unroll
                for (int ff = 0; ff < NOUT; ++ff) v[3 + ff] = w8[ff];
                float m = 0.f;
                #pragma unroll
                for (int j = 0; j < DD; ++j) m += v[j];
                m *= (1.0f / DD);
                float var = 0.f;
                #pragma unroll
                for (int j = 0; j < DD; ++j) { float d = v[j] - m; var += d * d; }
                var *= (1.0f / DD);
                float rs = rsqrtf(var + LN_EPS);
                #pragma unroll
                for (int j = 0; j < DD; ++j)
                    xn[lane * 72 + 22 + j] = f2bf((v[j] - m) * rs * s_g1[j] + s_b1[j]);
            }
        }
        __syncthreads();
    }
}

// ================= fallback (fp32 VALU, R3-proven) =================
#define MROW 4
#define NTF 1024
__global__ __launch_bounds__(NTF)
void solver_fb(const float* __restrict__ inputs,
               const float* __restrict__ g1v, const float* __restrict__ b1v,
               const float* __restrict__ ew1, const float* __restrict__ eb1,
               const float* __restrict__ ew2, const float* __restrict__ eb2,
               const float* __restrict__ uw,  const float* __restrict__ ub,
               const float* __restrict__ g2v, const float* __restrict__ b2v,
               const float* __restrict__ bww,
               const float* __restrict__ dw1, const float* __restrict__ db1,
               const float* __restrict__ dw2, const float* __restrict__ db2,
               const int* __restrict__ fixv,
               float* __restrict__ out)
{
    __shared__ float x33[MROW][K1];
    __shared__ float h1s[MROW * H2];
    __shared__ float hs[MROW * UU];
    __shared__ float combs[MROW][UU + 1];
    __shared__ float gs[MROW * H2];
    __shared__ float win[MROW][LBK][NOUT];
    __shared__ float redf[8192];
    __shared__ float red2[32][32];
    __shared__ float wred[16][3];
    __shared__ float rowstat[MROW][3];
    __shared__ float ynew[MROW][NOUT];
    float2* redf2 = reinterpret_cast<float2*>(redf);
    const int tid = threadIdx.x;
    const int b0 = blockIdx.x * MROW;
    const int fx0 = fixv[0], fx1 = fixv[1];
    if (tid < MROW * LBK * NOUT) {
        int r = tid / (LBK * NOUT);
        int rem = tid % (LBK * NOUT);
        int p = rem / NOUT, f = rem % NOUT;
        win[r][p][f] = inputs[((size_t)(b0 + r) * S_LEN + p) * FIN + 1 + f];
    }
    __syncthreads();
    for (int t = 0; t < NSTEP; ++t) {
        const int i = t + LBK;
        if (tid < MROW * LBK) {
            int r = tid / LBK, p = tid % LBK;
            int b = b0 + r;
            int tt = i - LBK + p;
            float ld = inputs[((size_t)b * S_LEN + tt) * FIN];
            float df = (tt > 0) ? ld - inputs[((size_t)b * S_LEN + tt - 1) * FIN] : 0.f;
            float v[DD];
            v[0] = ld; v[1] = ld; v[2] = df;
            #pragma unroll
            for (int f = 0; f < NOUT; ++f) v[3 + f] = win[r][p][f];
            float m = 0.f;
            #pragma unroll
            for (int j = 0; j < DD; ++j) m += v[j];
            m *= (1.0f / DD);
            float var = 0.f;
            #pragma unroll
            for (int j = 0; j < DD; ++j) { float d = v[j] - m; var += d * d; }
            var *= (1.0f / DD);
            float rs = rsqrtf(var + LN_EPS);
            #pragma unroll
            for (int j = 0; j < DD; ++j)
                x33[r][p * DD + j] = (v[j] - m) * rs * g1v[j] + b1v[j];
        }
        __syncthreads();
        {
            int cc = tid & 255, c0 = cc * 2;
            int ks = tid >> 8;
            int kbeg = ks * 8;
            int kend = (ks == 3) ? K1 : kbeg + 8;
            float2 acc[MROW];
            #pragma unroll
            for (int r = 0; r < MROW; ++r) acc[r] = make_float2(0.f, 0.f);
            for (int k = kbeg; k < kend; ++k) {
                float2 w = *reinterpret_cast<const float2*>(ew1 + (size_t)k * H2 + c0);
                #pragma unroll
                for (int r = 0; r < MROW; ++r) {
                    float xv = x33[r][k];
                    acc[r].x += xv * w.x; acc[r].y += xv * w.y;
                }
            }
            #pragma unroll
            for (int r = 0; r < MROW; ++r) redf2[ks * 1024 + r * 256 + cc] = acc[r];
        }
        __syncthreads();
        {
            #pragma unroll
            for (int jj = 0; jj < 2; ++jj) {
                int o = tid + jj * 1024;
                float v = redf[o] + redf[2048 + o] + redf[4096 + o] + redf[6144 + o] + eb1[o & 511];
                h1s[o] = tanhf(v);
            }
        }
        __syncthreads();
        {
            int cc = tid & 127, c0 = cc * 2;
            int ks = tid >> 7;
            int kbeg = ks * 64;
            float2 acc[MROW];
            #pragma unroll
            for (int r = 0; r < MROW; ++r) acc[r] = make_float2(0.f, 0.f);
            #pragma unroll 8
            for (int k = kbeg; k < kbeg + 64; ++k) {
                float2 w = *reinterpret_cast<const float2*>(ew2 + (size_t)k * UU + c0);
                #pragma unroll
                for (int r = 0; r < MROW; ++r) {
                    float hv = h1s[r * H2 + k];
                    acc[r].x += hv * w.x; acc[r].y += hv * w.y;
                }
            }
            #pragma unroll
            for (int r = 0; r < MROW; ++r) redf2[ks * 512 + r * 128 + cc] = acc[r];
        }
        __syncthreads();
        {
            int o = tid;
            float v = eb2[o & 255];
            #pragma unroll
            for (int ks = 0; ks < 8; ++ks) v += redf[ks * 1024 + o];
            hs[o] = v;
        }
        __syncthreads();
        {
            int cc = tid & 127, c0 = cc * 2;
            int ks = tid >> 7;
            int kbeg = ks * 32;
            float2 acc[MROW];
            #pragma unroll
            for (int r = 0; r < MROW; ++r) acc[r] = make_float2(0.f, 0.f);
            #pragma unroll 8
            for (int k = kbeg; k < kbeg + 32; ++k) {
                float2 w = *reinterpret_cast<const float2*>(uw + (size_t)k * UU + c0);
                #pragma unroll
                for (int r = 0; r < MROW; ++r) {
                    float hv = hs[r * UU + k];
                    acc[r].x += hv * w.x; acc[r].y += hv * w.y;
                }
            }
            #pragma unroll
            for (int r = 0; r < MROW; ++r) redf2[ks * 512 + r * 128 + cc] = acc[r];
        }
        __syncthreads();
        {
            int o = tid, r = o >> 8, c = o & 255;
            float v = ub[c];
            #pragma unroll
            for (int ks = 0; ks < 8; ++ks) v += redf[ks * 1024 + o];
            combs[r][c] = v;
        }
        __syncthreads();
        {
            int r = tid >> 8, c = tid & 255;
            float u = combs[r][c];
            float hb = hs[r * UU + c] * bww[c];
            float s0 = u, s1 = u * u, s2 = hb;
            #pragma unroll
            for (int mk = 1; mk < 64; mk <<= 1) {
                s0 += __shfl_xor(s0, mk);
                s1 += __shfl_xor(s1, mk);
                s2 += __shfl_xor(s2, mk);
            }
            if ((tid & 63) == 0) {
                int w = tid >> 6;
                wred[w][0] = s0; wred[w][1] = s1; wred[w][2] = s2;
            }
        }
        __syncthreads();
        if (tid < MROW) {
            int r = tid;
            float t0 = 0.f, t1 = 0.f, t2 = 0.f;
            #pragma unroll
            for (int w = 4 * r; w < 4 * r + 4; ++w) { t0 += wred[w][0]; t1 += wred[w][1]; t2 += wred[w][2]; }
            float mean = t0 * (1.0f / UU);
            float var = t1 * (1.0f / UU) - mean * mean;
            rowstat[r][0] = mean; rowstat[r][1] = rsqrtf(var + LN_EPS); rowstat[r][2] = t2;
        }
        __syncthreads();
        {
            int r = tid >> 8, c = tid & 255;
            float u = combs[r][c];
            combs[r][c] = (u - rowstat[r][0]) * rowstat[r][1] * g2v[c] + b2v[c];
            if (tid < MROW) combs[tid][UU] = rowstat[tid][2];
        }
        __syncthreads();
        {
            int cc = tid & 255, c0 = cc * 2;
            int ks = tid >> 8;
            int kbeg = ks * 64;
            int kend = (ks == 3) ? (UU + 1) : kbeg + 64;
            float2 acc[MROW];
            #pragma unroll
            for (int r = 0; r < MROW; ++r) acc[r] = make_float2(0.f, 0.f);
            #pragma unroll 8
            for (int k = kbeg; k < kend; ++k) {
                float2 w = *reinterpret_cast<const float2*>(dw1 + (size_t)k * H2 + c0);
                #pragma unroll
                for (int r = 0; r < MROW; ++r) {
                    float cv = combs[r][k];
                    acc[r].x += cv * w.x; acc[r].y += cv * w.y;
                }
            }
            #pragma unroll
            for (int r = 0; r < MROW; ++r) redf2[ks * 1024 + r * 256 + cc] = acc[r];
        }
        __syncthreads();
        {
            #pragma unroll
            for (int jj = 0; jj < 2; ++jj) {
                int o = tid + jj * 1024;
                float v = redf[o] + redf[2048 + o] + redf[4096 + o] + redf[6144 + o] + db1[o & 511];
                gs[o] = tanhf(v);
            }
        }
        __syncthreads();
        {
            int o = tid & 31, kc = tid >> 5;
            int r = o >> 3, f = o & 7;
            int kbeg = kc * 16;
            float p = 0.f;
            #pragma unroll 4
            for (int k = kbeg; k < kbeg + 16; ++k)
                p += gs[r * H2 + k] * dw2[(size_t)k * NOUT + f];
            red2[kc][o] = p;
        }
        __syncthreads();
        if (tid < 32) {
            int o = tid, r = o >> 3, f = o & 7;
            int b = b0 + r;
            float y = db2[f];
            #pragma unroll
            for (int kc = 0; kc < 32; ++kc) y += red2[kc][o];
            if (f == fx0) y = inputs[((size_t)b * S_LEN + i + 1) * FIN + 1 + fx0];
            if (f == fx1) y = inputs[((size_t)b * S_LEN + i + 1) * FIN + 1 + fx1];
            ynew[r][f] = y;
            out[((size_t)(f * 1024 + b)) * NSTEP + t] = y;
        }
        __syncthreads();
        {
            float wshift = 0.f;
            int sr = 0, sp = 0, sf = 0;
            bool doshift = tid < MROW * LBK * NOUT;
            if (doshift) {
                sr = tid / (LBK * NOUT);
                int rem = tid % (LBK * NOUT);
                sp = rem / NOUT; sf = rem % NOUT;
                wshift = (sp < LBK - 1) ? win[sr][sp + 1][sf] : ynew[sr][sf];
            }
            __syncthreads();
            if (doshift) win[sr][sp][sf] = wshift;
        }
        __syncthreads();
    }
}

extern "C" void kernel_launch(void* const* d_in, const int* in_sizes, int n_in,
                              void* d_out, int out_size, void* d_ws, size_t ws_size,
                              hipStream_t stream) {
    (void)in_sizes; (void)n_in; (void)out_size;
    const bool use_mfma = (d_ws != nullptr) && (ws_size >= (size_t)W_TOT * sizeof(unsigned short));
    if (use_mfma) {
        unsigned short* pool = (unsigned short*)d_ws;
        convw<<<(W_TOT + 255) / 256, 256, 0, stream>>>(
            (const float*)d_in[3], (const float*)d_in[5], (const float*)d_in[7],
            (const float*)d_in[12], (const float*)d_in[14], pool);
        convaux<<<4, 256, 0, stream>>>(
            (const float*)d_in[5], (const float*)d_in[6], (const float*)d_in[7],
            (const float*)d_in[8], (const float*)d_in[11], (float*)(pool + O_UW));
        solver<<<GRID, 1024, 0, stream>>>(
            (const float*)d_in[0], pool,
            (const float*)d_in[1], (const float*)d_in[2],
            (const float*)d_in[4], (const float*)d_in[6],
            (const float*)d_in[8], (const float*)d_in[9],
            (const float*)d_in[10], (const float*)d_in[11],
            (const float*)d_in[12], (const float*)d_in[13],
            (const float*)d_in[15], (const int*)d_in[16],
            (float*)d_out);
    } else {
        solver_fb<<<256, NTF, 0, stream>>>(
            (const float*)d_in[0],
            (const float*)d_in[1], (const float*)d_in[2],
            (const float*)d_in[3], (const float*)d_in[4],
            (const float*)d_in[5], (const float*)d_in[6],
            (const float*)d_in[7], (const float*)d_in[8],
            (const float*)d_in[9], (const float*)d_in[10],
            (const float*)d_in[11],
            (const float*)d_in[12], (const float*)d_in[13],
            (const float*)d_in[14], (const float*)d_in[15],
            (const int*)d_in[16],
            (float*)d_out);
    }
}